// Round 1
// baseline (1333.023 us; speedup 1.0000x reference)
//
#include <hip/hip_runtime.h>
#include <math.h>

// Problem constants
#define BQ 128
#define SQ 100
#define EDIM 1024
#define HH 16
#define LL 48
#define DD 64
#define MM 64
#define BS (BQ*SQ)        // 12800 rows
#define UNITS (BS*HH)     // 204800 (b,s,h) units

typedef __bf16 bf16_t;
typedef bf16_t bf16x8 __attribute__((ext_vector_type(8)));
typedef float f32x4 __attribute__((ext_vector_type(4)));

// Workspace byte offsets (total ~208.5 MB)
#define Q_OFF   0ull            // 52,428,800 B  (q -> phi_q in place)
#define K_OFF   52428800ull     // 52,428,800 B  (k -> phi_k in place)
#define V_OFF   104857600ull    // 52,428,800 B  (v; later A1 33.5MB)
#define PKL_OFF 157286400ull    // 25,165,824 B
#define VL_OFF  182452224ull    // 25,165,824 B
#define DEN_OFF 207618048ull    // 819,200 B
#define XB_OFF  157286400ull    // bf16 x (26.2MB) — overlaps PKL (dead by then)
#define WB_OFF  183500800ull    // bf16 Wcat (6.3MB) — overlaps VL (dead by then)
#define SC_OFF  208437248ull    // 16 B scalars: ssq_q, ssq_k, inv_qn, inv_kn

// ---------------- convert x -> bf16 ----------------
__global__ __launch_bounds__(256)
void kconv_x(const float* __restrict__ x, bf16_t* __restrict__ xb, int n4) {
    int i = blockIdx.x * blockDim.x + threadIdx.x;
    int stride = gridDim.x * blockDim.x;
    const f32x4* x4 = (const f32x4*)x;
    for (; i < n4; i += stride) {
        f32x4 v = x4[i];
        bf16_t* o = xb + 4*(size_t)i;
        o[0] = (bf16_t)v[0]; o[1] = (bf16_t)v[1];
        o[2] = (bf16_t)v[2]; o[3] = (bf16_t)v[3];
    }
}

// ---------------- convert Wq|Wk|Wv -> bf16 concatenated [3072][1024] ----------------
__global__ __launch_bounds__(256)
void kconv_w(const float* __restrict__ Wq, const float* __restrict__ Wk,
             const float* __restrict__ Wv, bf16_t* __restrict__ wb, int n4) {
    int i = blockIdx.x * blockDim.x + threadIdx.x;
    int stride = gridDim.x * blockDim.x;
    for (; i < n4; i += stride) {
        int f = i * 4;
        int row = f >> 10;
        int col = f & 1023;
        const float* src = (row < 1024) ? Wq : ((row < 2048) ? Wk : Wv);
        const f32x4 v = *(const f32x4*)(src + ((size_t)(row & 1023) << 10) + col);
        bf16_t* o = wb + (size_t)f;
        o[0] = (bf16_t)v[0]; o[1] = (bf16_t)v[1];
        o[2] = (bf16_t)v[2]; o[3] = (bf16_t)v[3];
    }
}

// ---------------- fused QKV GEMM: out[r][c]=sum_k x[r][k]*Wcat[c][k] + b[c] ----------------
// block = 256 (4 waves, 2x2), block tile 128x128, wave tile 64x64 (4x4 MFMA frags)
__global__ __launch_bounds__(256)
void kgemm(const bf16_t* __restrict__ xb, const bf16_t* __restrict__ wb,
           const float* __restrict__ bq, const float* __restrict__ bk,
           const float* __restrict__ bv,
           float* __restrict__ qb, float* __restrict__ kb, float* __restrict__ vb,
           float* __restrict__ ssq) {
    const int lane = threadIdx.x & 63;
    const int wave = threadIdx.x >> 6;
    const int row0 = blockIdx.y * 128 + (wave >> 1) * 64;
    const int col0 = blockIdx.x * 128 + (wave & 1) * 64;
    const int ar = lane & 15;
    const int kg = lane >> 4;

    f32x4 acc[4][4];
#pragma unroll
    for (int m = 0; m < 4; m++)
#pragma unroll
        for (int n = 0; n < 4; n++)
            acc[m][n] = (f32x4){0.f, 0.f, 0.f, 0.f};

    const bf16_t* ap[4];
    const bf16_t* bp[4];
#pragma unroll
    for (int m = 0; m < 4; m++)
        ap[m] = xb + (size_t)(row0 + m*16 + ar) * 1024 + kg * 8;
#pragma unroll
    for (int n = 0; n < 4; n++)
        bp[n] = wb + (size_t)(col0 + n*16 + ar) * 1024 + kg * 8;

    for (int k = 0; k < 1024; k += 32) {
        bf16x8 a[4], b[4];
#pragma unroll
        for (int m = 0; m < 4; m++) a[m] = *(const bf16x8*)(ap[m] + k);
#pragma unroll
        for (int n = 0; n < 4; n++) b[n] = *(const bf16x8*)(bp[n] + k);
#pragma unroll
        for (int m = 0; m < 4; m++)
#pragma unroll
            for (int n = 0; n < 4; n++)
                acc[m][n] = __builtin_amdgcn_mfma_f32_16x16x32_bf16(
                    a[m], b[n], acc[m][n], 0, 0, 0);
    }

    float s0 = 0.f, s1 = 0.f;
#pragma unroll
    for (int n = 0; n < 4; n++) {
        const int c = col0 + n*16 + ar;
        const int which = c >> 10;           // uniform per fragment
        const int cc = c & 1023;
        const float bias = (which == 0 ? bq : (which == 1 ? bk : bv))[cc];
        float* ob = (which == 0 ? qb : (which == 1 ? kb : vb));
#pragma unroll
        for (int m = 0; m < 4; m++) {
#pragma unroll
            for (int j = 0; j < 4; j++) {
                const int r = row0 + m*16 + kg*4 + j;
                const float val = acc[m][n][j] + bias;
                ob[(size_t)r * 1024 + cc] = val;
                if (which == 0) s0 += val * val;
                else if (which == 1) s1 += val * val;
            }
        }
    }
    // wave reduction of sum-of-squares, then atomics
    for (int off = 32; off; off >>= 1) {
        s0 += __shfl_xor(s0, off);
        s1 += __shfl_xor(s1, off);
    }
    if (lane == 0) {
        if (s0 != 0.f) atomicAdd(ssq + 0, s0);
        if (s1 != 0.f) atomicAdd(ssq + 1, s1);
    }
}

// ---------------- finalize norms ----------------
__global__ void knorm(float* sc) {
    if (threadIdx.x == 0) {
        sc[2] = rsqrtf(sc[0]);
        sc[3] = rsqrtf(sc[1]);
    }
}

// ---------------- phi kernel: wave per (b,s,h); phi_q/phi_k in place; den ----------------
__global__ __launch_bounds__(256)
void kphi(float* __restrict__ qb, float* __restrict__ kb,
          const float* __restrict__ Wrf, float* __restrict__ den,
          const float* __restrict__ sc) {
    const int unit = blockIdx.x * 4 + (threadIdx.x >> 6);
    const int lane = threadIdx.x & 63;
    const int h = unit & 15;   // unit = ((b*100+s)*16 + h)

    const f32x4* wv = (const f32x4*)(Wrf + ((size_t)h * 64 + lane) * 64);
    const f32x4* qv = (const f32x4*)(qb + (size_t)unit * 64);
    const f32x4* kv = (const f32x4*)(kb + (size_t)unit * 64);

    float pq = 0.f, pk = 0.f;
#pragma unroll
    for (int i = 0; i < 16; i++) {
        f32x4 w = wv[i];
        f32x4 q = qv[i];
        f32x4 kk = kv[i];
        pq += w[0]*q[0] + w[1]*q[1] + w[2]*q[2] + w[3]*q[3];
        pk += w[0]*kk[0] + w[1]*kk[1] + w[2]*kk[2] + w[3]*kk[3];
    }
    const float CPHI = 0.009477041545882225f;  // exp(-0.5)/64
    const float phq = expf(pq * sc[2]) * CPHI;
    const float phk = expf(pk * sc[3]) * CPHI;

    float t = phq * phk;
    for (int off = 32; off; off >>= 1) t += __shfl_xor(t, off);
    if (lane == 0) den[unit] = t;

    qb[(size_t)unit * 64 + lane] = phq;   // all reads happened above (wave-lockstep)
    kb[(size_t)unit * 64 + lane] = phk;
}

// ---------------- pkl[b,h,l,m] = sum_s phi_k * E ; vl[b,h,l,d] = sum_s v * F ----------------
__global__ __launch_bounds__(256)
void kpklvl(const float* __restrict__ phk, const float* __restrict__ vb,
            const float* __restrict__ E, const float* __restrict__ F,
            float* __restrict__ pkl, float* __restrict__ vl) {
    __shared__ float sph[SQ * 64];
    __shared__ float svv[SQ * 64];
    const int bh = blockIdx.x;            // b*16 + h
    const int b = bh >> 4, h = bh & 15;

    for (int t = threadIdx.x; t < SQ * 64; t += 256) {
        const int s = t >> 6, m = t & 63;
        const size_t g = ((size_t)(b * SQ + s) * 16 + h) * 64 + m;
        sph[t] = phk[g];
        svv[t] = vb[g];
    }
    __syncthreads();

    for (int t = threadIdx.x; t < LL * 64; t += 256) {
        const int l = t >> 6, m = t & 63;
        float a1 = 0.f, a2 = 0.f;
        for (int s = 0; s < SQ; s++) {
            const float e = E[s * LL + l];
            const float f = F[s * LL + l];
            a1 += sph[s * 64 + m] * e;
            a2 += svv[s * 64 + m] * f;
        }
        const size_t o = ((size_t)bh * LL + l) * 64 + m;
        pkl[o] = a1;
        vl[o] = a2;
    }
}

// ---------------- A1[b,h,m,d] = sum_l pkl[l][m] * vl[l][d] ----------------
__global__ __launch_bounds__(256)
void ka1(const float* __restrict__ pkl, const float* __restrict__ vl,
         float* __restrict__ A1) {
    __shared__ float sp[LL * 64];
    __shared__ float sv[LL * 64];
    const int bh = blockIdx.x;
    for (int t = threadIdx.x; t < LL * 64; t += 256) {
        const size_t g = (size_t)bh * LL * 64 + t;
        sp[t] = pkl[g];
        sv[t] = vl[g];
    }
    __syncthreads();

    const int m = threadIdx.x >> 2;
    const int dg = (threadIdx.x & 3) * 16;
    float acc[16];
#pragma unroll
    for (int j = 0; j < 16; j++) acc[j] = 0.f;

    for (int l = 0; l < LL; l++) {
        const float a = sp[l * 64 + m];
        const float* vrow = &sv[l * 64 + dg];
#pragma unroll
        for (int j = 0; j < 16; j++) acc[j] += a * vrow[j];
    }
    float* o = A1 + (size_t)bh * 4096 + (size_t)m * 64 + dg;
#pragma unroll
    for (int j = 0; j < 16; j++) o[j] = acc[j];
}

// ---------------- final: out[unit*64+d] = (sum_m phi_q[m]*A1[m][d]) / den ----------------
__global__ __launch_bounds__(256)
void kfinal(const float* __restrict__ phq, const float* __restrict__ A1,
            const float* __restrict__ den, float* __restrict__ out) {
    const int unit = blockIdx.x * 4 + (threadIdx.x >> 6);
    const int lane = threadIdx.x & 63;
    const int h = unit & 15;
    const int b = unit / (SQ * 16);
    const int bh = b * 16 + h;

    const float* a = A1 + (size_t)bh * 4096;
    const float* p = phq + (size_t)unit * 64;
    float accv = 0.f;
#pragma unroll 4
    for (int m = 0; m < 64; m++) accv += p[m] * a[(size_t)m * 64 + lane];
    out[(size_t)unit * 64 + lane] = accv / den[unit];
}

extern "C" void kernel_launch(void* const* d_in, const int* in_sizes, int n_in,
                              void* d_out, int out_size, void* d_ws, size_t ws_size,
                              hipStream_t stream) {
    const float* x   = (const float*)d_in[0];
    const float* Wq  = (const float*)d_in[1];
    const float* bq  = (const float*)d_in[2];
    const float* Wk  = (const float*)d_in[3];
    const float* bk  = (const float*)d_in[4];
    const float* Wv  = (const float*)d_in[5];
    const float* bv  = (const float*)d_in[6];
    const float* Wrf = (const float*)d_in[7];
    const float* E   = (const float*)d_in[8];
    const float* F   = (const float*)d_in[9];
    float* out = (float*)d_out;

    char* ws = (char*)d_ws;
    float*  qb  = (float*)(ws + Q_OFF);
    float*  kb  = (float*)(ws + K_OFF);
    float*  vb  = (float*)(ws + V_OFF);
    float*  pkl = (float*)(ws + PKL_OFF);
    float*  vl  = (float*)(ws + VL_OFF);
    float*  den = (float*)(ws + DEN_OFF);
    bf16_t* xb  = (bf16_t*)(ws + XB_OFF);
    bf16_t* wb  = (bf16_t*)(ws + WB_OFF);
    float*  sc  = (float*)(ws + SC_OFF);
    float*  A1  = vb;  // reuse v region after vl is computed

    hipMemsetAsync(sc, 0, 16, stream);
    kconv_x<<<2048, 256, 0, stream>>>(x, xb, BS * 1024 / 4);
    kconv_w<<<1024, 256, 0, stream>>>(Wq, Wk, Wv, wb, 3 * 1024 * 1024 / 4);

    dim3 ggrid(24, 100);   // 3072/128 cols x 12800/128 rows
    kgemm<<<ggrid, 256, 0, stream>>>(xb, wb, bq, bk, bv, qb, kb, vb, sc);

    knorm<<<1, 64, 0, stream>>>(sc);
    kphi<<<UNITS / 4, 256, 0, stream>>>(qb, kb, Wrf, den, sc);
    kpklvl<<<BQ * HH, 256, 0, stream>>>(kb, vb, E, F, pkl, vl);
    ka1<<<BQ * HH, 256, 0, stream>>>(pkl, vl, A1);
    kfinal<<<UNITS / 4, 256, 0, stream>>>(qb, A1, den, out);
}

// Round 2
// 784.628 us; speedup vs baseline: 1.6989x; 1.6989x over previous
//
#include <hip/hip_runtime.h>
#include <math.h>

// Problem constants
#define BQ 128
#define SQ 100
#define EDIM 1024
#define HH 16
#define LL 48
#define DD 64
#define MM 64
#define BS (BQ*SQ)        // 12800 rows
#define UNITS (BS*HH)     // 204800 (b,s,h) units

typedef __bf16 bf16_t;
typedef bf16_t bf16x8 __attribute__((ext_vector_type(8)));
typedef float f32x4 __attribute__((ext_vector_type(4)));

// Workspace byte offsets (total ~208.5 MB, same footprint as R0)
#define PHQ_OFF  0ull            // 26,214,400 B  phi_q bf16
#define PHK_OFF  26214400ull     // 26,214,400 B  phi_k bf16
#define QBH_OFF  52428800ull     // 26,214,400 B  q bf16 (unnormalized)
#define KBH_OFF  78643200ull     // 26,214,400 B  k bf16 (unnormalized)
#define V_OFF    104857600ull    // 52,428,800 B  v fp32; A1 (33.5MB) reuses after kpklvl
#define PKL_OFF  157286400ull    // 25,165,824 B
#define VL_OFF   182452224ull    // 25,165,824 B
#define DEN_OFF  207618048ull    // 819,200 B
#define XB_OFF   157286400ull    // bf16 x (26.2MB) — overlaps PKL (dead by kpklvl)
#define WB_OFF   183500800ull    // bf16 Wcat (6.3MB) — inside VL region (dead by kpklvl)
#define WRFB_OFF 189792256ull    // bf16 Wrf (128KB) — inside VL region (dead by kpklvl)
#define SC_OFF   208437248ull    // 16 B scalars: ssq_q, ssq_k, inv_qn, inv_kn

// ---------------- convert x -> bf16 ----------------
__global__ __launch_bounds__(256)
void kconv_x(const float* __restrict__ x, bf16_t* __restrict__ xb, int n4) {
    int i = blockIdx.x * blockDim.x + threadIdx.x;
    int stride = gridDim.x * blockDim.x;
    const f32x4* x4 = (const f32x4*)x;
    for (; i < n4; i += stride) {
        f32x4 v = x4[i];
        bf16_t* o = xb + 4*(size_t)i;
        o[0] = (bf16_t)v[0]; o[1] = (bf16_t)v[1];
        o[2] = (bf16_t)v[2]; o[3] = (bf16_t)v[3];
    }
}

// ---------------- convert Wq|Wk|Wv -> bf16 concatenated [3072][1024] ----------------
__global__ __launch_bounds__(256)
void kconv_w(const float* __restrict__ Wq, const float* __restrict__ Wk,
             const float* __restrict__ Wv, bf16_t* __restrict__ wb, int n4) {
    int i = blockIdx.x * blockDim.x + threadIdx.x;
    int stride = gridDim.x * blockDim.x;
    for (; i < n4; i += stride) {
        int f = i * 4;
        int row = f >> 10;
        int col = f & 1023;
        const float* src = (row < 1024) ? Wq : ((row < 2048) ? Wk : Wv);
        const f32x4 v = *(const f32x4*)(src + ((size_t)(row & 1023) << 10) + col);
        bf16_t* o = wb + (size_t)f;
        o[0] = (bf16_t)v[0]; o[1] = (bf16_t)v[1];
        o[2] = (bf16_t)v[2]; o[3] = (bf16_t)v[3];
    }
}

// ---------------- convert Wrf -> bf16 [16][64][64] ----------------
__global__ __launch_bounds__(256)
void kconv_wrf(const float* __restrict__ w, bf16_t* __restrict__ o, int n4) {
    int i = blockIdx.x * blockDim.x + threadIdx.x;
    if (i >= n4) return;
    f32x4 v = ((const f32x4*)w)[i];
    bf16_t* p = o + 4*(size_t)i;
    p[0] = (bf16_t)v[0]; p[1] = (bf16_t)v[1];
    p[2] = (bf16_t)v[2]; p[3] = (bf16_t)v[3];
}

// ---------------- fused QKV GEMM: out[r][c]=sum_k x[r][k]*Wcat[c][k] + b[c] ----------------
// q,k written as bf16 (feed phi MFMA); v as fp32. ssq accumulated from fp32 values.
__global__ __launch_bounds__(256)
void kgemm(const bf16_t* __restrict__ xb, const bf16_t* __restrict__ wb,
           const float* __restrict__ bq, const float* __restrict__ bk,
           const float* __restrict__ bv,
           bf16_t* __restrict__ qbh, bf16_t* __restrict__ kbh,
           float* __restrict__ vb, float* __restrict__ ssq) {
    const int lane = threadIdx.x & 63;
    const int wave = threadIdx.x >> 6;
    const int row0 = blockIdx.y * 128 + (wave >> 1) * 64;
    const int col0 = blockIdx.x * 128 + (wave & 1) * 64;
    const int ar = lane & 15;
    const int kg = lane >> 4;

    f32x4 acc[4][4];
#pragma unroll
    for (int m = 0; m < 4; m++)
#pragma unroll
        for (int n = 0; n < 4; n++)
            acc[m][n] = (f32x4){0.f, 0.f, 0.f, 0.f};

    const bf16_t* ap[4];
    const bf16_t* bp[4];
#pragma unroll
    for (int m = 0; m < 4; m++)
        ap[m] = xb + (size_t)(row0 + m*16 + ar) * 1024 + kg * 8;
#pragma unroll
    for (int n = 0; n < 4; n++)
        bp[n] = wb + (size_t)(col0 + n*16 + ar) * 1024 + kg * 8;

    for (int k = 0; k < 1024; k += 32) {
        bf16x8 a[4], b[4];
#pragma unroll
        for (int m = 0; m < 4; m++) a[m] = *(const bf16x8*)(ap[m] + k);
#pragma unroll
        for (int n = 0; n < 4; n++) b[n] = *(const bf16x8*)(bp[n] + k);
#pragma unroll
        for (int m = 0; m < 4; m++)
#pragma unroll
            for (int n = 0; n < 4; n++)
                acc[m][n] = __builtin_amdgcn_mfma_f32_16x16x32_bf16(
                    a[m], b[n], acc[m][n], 0, 0, 0);
    }

    float s0 = 0.f, s1 = 0.f;
#pragma unroll
    for (int n = 0; n < 4; n++) {
        const int c = col0 + n*16 + ar;
        const int which = c >> 10;           // uniform per fragment
        const int cc = c & 1023;
        const float bias = (which == 0 ? bq : (which == 1 ? bk : bv))[cc];
#pragma unroll
        for (int m = 0; m < 4; m++) {
#pragma unroll
            for (int j = 0; j < 4; j++) {
                const int r = row0 + m*16 + kg*4 + j;
                const float val = acc[m][n][j] + bias;
                if (which == 0) {
                    qbh[(size_t)r * 1024 + cc] = (bf16_t)val;
                    s0 += val * val;
                } else if (which == 1) {
                    kbh[(size_t)r * 1024 + cc] = (bf16_t)val;
                    s1 += val * val;
                } else {
                    vb[(size_t)r * 1024 + cc] = val;
                }
            }
        }
    }
    // wave reduction of sum-of-squares, then atomics
    for (int off = 32; off; off >>= 1) {
        s0 += __shfl_xor(s0, off);
        s1 += __shfl_xor(s1, off);
    }
    if (lane == 0) {
        if (s0 != 0.f) atomicAdd(ssq + 0, s0);
        if (s1 != 0.f) atomicAdd(ssq + 1, s1);
    }
}

// ---------------- finalize norms ----------------
__global__ void knorm(float* sc) {
    if (threadIdx.x == 0) {
        sc[2] = rsqrtf(sc[0]);
        sc[3] = rsqrtf(sc[1]);
    }
}

// ---------------- phi via MFMA: per (h, bs-tile); phi_q/phi_k bf16 + den ----------------
// proj[bs,m] = sum_d q[bs,h,d]*Wrf[h,m,d]; wave tile = 64 bs-rows x 64 m, K=64
__global__ __launch_bounds__(256)
void kphi_mfma(const bf16_t* __restrict__ qbh, const bf16_t* __restrict__ kbh,
               const bf16_t* __restrict__ wrfb, const float* __restrict__ sc,
               bf16_t* __restrict__ phqb, bf16_t* __restrict__ phkb,
               float* __restrict__ den) {
    const int lane = threadIdx.x & 63;
    const int wid  = threadIdx.x >> 6;
    const int h    = blockIdx.y;
    const int bs0  = blockIdx.x * 256 + wid * 64;
    const int ar = lane & 15;
    const int kg = lane >> 4;

    // B fragments: Wrf[h][m][d], m = cf*16+ar, d = ks*32 + kg*8 + e  (resident)
    bf16x8 bfr[4][2];
#pragma unroll
    for (int cf = 0; cf < 4; cf++)
#pragma unroll
        for (int ks = 0; ks < 2; ks++)
            bfr[cf][ks] = *(const bf16x8*)(wrfb +
                ((size_t)(h * 64 + cf * 16 + ar) * 64 + ks * 32 + kg * 8));

    f32x4 aq[4][4], ak[4][4];
#pragma unroll
    for (int rf = 0; rf < 4; rf++)
#pragma unroll
        for (int cf = 0; cf < 4; cf++) {
            aq[rf][cf] = (f32x4){0.f, 0.f, 0.f, 0.f};
            ak[rf][cf] = (f32x4){0.f, 0.f, 0.f, 0.f};
        }

#pragma unroll
    for (int rf = 0; rf < 4; rf++) {
        const size_t urow = ((size_t)(bs0 + rf*16 + ar) * 16 + h) * 64 + kg * 8;
        const bf16x8 a0 = *(const bf16x8*)(qbh + urow);
        const bf16x8 a1 = *(const bf16x8*)(qbh + urow + 32);
        const bf16x8 c0 = *(const bf16x8*)(kbh + urow);
        const bf16x8 c1 = *(const bf16x8*)(kbh + urow + 32);
#pragma unroll
        for (int cf = 0; cf < 4; cf++) {
            aq[rf][cf] = __builtin_amdgcn_mfma_f32_16x16x32_bf16(a0, bfr[cf][0], aq[rf][cf], 0, 0, 0);
            aq[rf][cf] = __builtin_amdgcn_mfma_f32_16x16x32_bf16(a1, bfr[cf][1], aq[rf][cf], 0, 0, 0);
            ak[rf][cf] = __builtin_amdgcn_mfma_f32_16x16x32_bf16(c0, bfr[cf][0], ak[rf][cf], 0, 0, 0);
            ak[rf][cf] = __builtin_amdgcn_mfma_f32_16x16x32_bf16(c1, bfr[cf][1], ak[rf][cf], 0, 0, 0);
        }
    }

    const float qs = sc[2];
    const float ksc = sc[3];
    const float CPHI = 0.009477041545882225f;  // exp(-0.5)/64

#pragma unroll
    for (int rf = 0; rf < 4; rf++) {
        float t[4] = {0.f, 0.f, 0.f, 0.f};
#pragma unroll
        for (int cf = 0; cf < 4; cf++) {
#pragma unroll
            for (int j = 0; j < 4; j++) {
                const float vq = expf(aq[rf][cf][j] * qs) * CPHI;
                const float vk = expf(ak[rf][cf][j] * ksc) * CPHI;
                const int bs = bs0 + rf*16 + kg*4 + j;
                const size_t o = ((size_t)bs * 16 + h) * 64 + cf * 16 + ar;
                phqb[o] = (bf16_t)vq;
                phkb[o] = (bf16_t)vk;
                t[j] += vq * vk;
            }
        }
#pragma unroll
        for (int j = 0; j < 4; j++) {
            float tt = t[j];
            tt += __shfl_xor(tt, 1);
            tt += __shfl_xor(tt, 2);
            tt += __shfl_xor(tt, 4);
            tt += __shfl_xor(tt, 8);
            if (ar == 0) {
                const int bs = bs0 + rf*16 + kg*4 + j;
                den[bs * 16 + h] = tt;
            }
        }
    }
}

// ---------------- pkl[b,h,l,m] = sum_s phi_k * E ; vl[b,h,l,d] = sum_s v * F ----------------
__global__ __launch_bounds__(256)
void kpklvl(const bf16_t* __restrict__ phk, const float* __restrict__ vb,
            const float* __restrict__ E, const float* __restrict__ F,
            float* __restrict__ pkl, float* __restrict__ vl) {
    __shared__ float sph[SQ * 64];
    __shared__ float svv[SQ * 64];
    const int bh = blockIdx.x;            // b*16 + h
    const int b = bh >> 4, h = bh & 15;

    for (int t = threadIdx.x; t < SQ * 64; t += 256) {
        const int s = t >> 6, m = t & 63;
        const size_t g = ((size_t)(b * SQ + s) * 16 + h) * 64 + m;
        sph[t] = (float)phk[g];
        svv[t] = vb[g];
    }
    __syncthreads();

    for (int t = threadIdx.x; t < LL * 64; t += 256) {
        const int l = t >> 6, m = t & 63;
        float a1 = 0.f, a2 = 0.f;
        for (int s = 0; s < SQ; s++) {
            const float e = E[s * LL + l];
            const float f = F[s * LL + l];
            a1 += sph[s * 64 + m] * e;
            a2 += svv[s * 64 + m] * f;
        }
        const size_t o = ((size_t)bh * LL + l) * 64 + m;
        pkl[o] = a1;
        vl[o] = a2;
    }
}

// ---------------- A1[b,h,m,d] = sum_l pkl[l][m] * vl[l][d] ----------------
__global__ __launch_bounds__(256)
void ka1(const float* __restrict__ pkl, const float* __restrict__ vl,
         float* __restrict__ A1) {
    __shared__ float sp[LL * 64];
    __shared__ float sv[LL * 64];
    const int bh = blockIdx.x;
    for (int t = threadIdx.x; t < LL * 64; t += 256) {
        const size_t g = (size_t)bh * LL * 64 + t;
        sp[t] = pkl[g];
        sv[t] = vl[g];
    }
    __syncthreads();

    const int m = threadIdx.x >> 2;
    const int dg = (threadIdx.x & 3) * 16;
    float acc[16];
#pragma unroll
    for (int j = 0; j < 16; j++) acc[j] = 0.f;

    for (int l = 0; l < LL; l++) {
        const float a = sp[l * 64 + m];
        const float* vrow = &sv[l * 64 + dg];
#pragma unroll
        for (int j = 0; j < 16; j++) acc[j] += a * vrow[j];
    }
    float* o = A1 + (size_t)bh * 4096 + (size_t)m * 64 + dg;
#pragma unroll
    for (int j = 0; j < 16; j++) o[j] = acc[j];
}

// ---------------- final: out[unit*64+d] = (sum_m phi_q[m]*A1[m][d]) / den ----------------
__global__ __launch_bounds__(256)
void kfinal(const bf16_t* __restrict__ phq, const float* __restrict__ A1,
            const float* __restrict__ den, float* __restrict__ out) {
    const int unit = blockIdx.x * 4 + (threadIdx.x >> 6);
    const int lane = threadIdx.x & 63;
    const int h = unit & 15;
    const int b = unit / (SQ * 16);
    const int bh = b * 16 + h;

    const float* a = A1 + (size_t)bh * 4096;
    const bf16_t* p = phq + (size_t)unit * 64;
    float accv = 0.f;
#pragma unroll 4
    for (int m = 0; m < 64; m++) accv += (float)p[m] * a[(size_t)m * 64 + lane];
    out[(size_t)unit * 64 + lane] = accv / den[unit];
}

extern "C" void kernel_launch(void* const* d_in, const int* in_sizes, int n_in,
                              void* d_out, int out_size, void* d_ws, size_t ws_size,
                              hipStream_t stream) {
    const float* x   = (const float*)d_in[0];
    const float* Wq  = (const float*)d_in[1];
    const float* bq  = (const float*)d_in[2];
    const float* Wk  = (const float*)d_in[3];
    const float* bk  = (const float*)d_in[4];
    const float* Wv  = (const float*)d_in[5];
    const float* bv  = (const float*)d_in[6];
    const float* Wrf = (const float*)d_in[7];
    const float* E   = (const float*)d_in[8];
    const float* F   = (const float*)d_in[9];
    float* out = (float*)d_out;

    char* ws = (char*)d_ws;
    bf16_t* phqb = (bf16_t*)(ws + PHQ_OFF);
    bf16_t* phkb = (bf16_t*)(ws + PHK_OFF);
    bf16_t* qbh  = (bf16_t*)(ws + QBH_OFF);
    bf16_t* kbh  = (bf16_t*)(ws + KBH_OFF);
    float*  vb   = (float*)(ws + V_OFF);
    float*  pkl  = (float*)(ws + PKL_OFF);
    float*  vl   = (float*)(ws + VL_OFF);
    float*  den  = (float*)(ws + DEN_OFF);
    bf16_t* xb   = (bf16_t*)(ws + XB_OFF);
    bf16_t* wb   = (bf16_t*)(ws + WB_OFF);
    bf16_t* wrfb = (bf16_t*)(ws + WRFB_OFF);
    float*  sc   = (float*)(ws + SC_OFF);
    float*  A1   = vb;  // reuse v region after vl is computed

    hipMemsetAsync(sc, 0, 16, stream);
    kconv_x<<<2048, 256, 0, stream>>>(x, xb, BS * 1024 / 4);
    kconv_w<<<1024, 256, 0, stream>>>(Wq, Wk, Wv, wb, 3 * 1024 * 1024 / 4);
    kconv_wrf<<<64, 256, 0, stream>>>(Wrf, wrfb, HH * MM * DD / 4);

    dim3 ggrid(24, 100);   // 3072/128 cols x 12800/128 rows
    kgemm<<<ggrid, 256, 0, stream>>>(xb, wb, bq, bk, bv, qbh, kbh, vb, sc);

    knorm<<<1, 64, 0, stream>>>(sc);
    dim3 pgrid(50, 16);    // 12800/256 bs-tiles x 16 heads
    kphi_mfma<<<pgrid, 256, 0, stream>>>(qbh, kbh, wrfb, sc, phqb, phkb, den);
    kpklvl<<<BQ * HH, 256, 0, stream>>>(phkb, vb, E, F, pkl, vl);
    ka1<<<BQ * HH, 256, 0, stream>>>(pkl, vl, A1);
    kfinal<<<UNITS / 4, 256, 0, stream>>>(phqb, A1, den, out);
}

// Round 3
// 599.315 us; speedup vs baseline: 2.2242x; 1.3092x over previous
//
#include <hip/hip_runtime.h>
#include <math.h>

// Problem constants
#define BQ 128
#define SQ 100
#define EDIM 1024
#define HH 16
#define LL 48
#define DD 64
#define MM 64
#define BS (BQ*SQ)        // 12800 rows
#define UNITS (BS*HH)     // 204800 (b,s,h) units

typedef __bf16 bf16_t;
typedef bf16_t bf16x8 __attribute__((ext_vector_type(8)));
typedef float f32x4 __attribute__((ext_vector_type(4)));

// Workspace byte offsets (peak ~182.2 MB, under proven 208.4 MB)
#define QBH_OFF  0ull            // 26,214,400 B q bf16 (dead after kphi)
#define KBH_OFF  26214400ull     // 26,214,400 B k bf16 (dead after kphi)
#define VBH_OFF  52428800ull     // 26,214,400 B v bf16 (dead after kpklvl)
#define XB_OFF   78643200ull     // 26,214,400 B x bf16 (dead after kgemm)
#define PHQ_OFF  78643200ull     // phi_q bf16, written in kphi (over dead XB)
#define WB_OFF   104857600ull    // 6,291,456 B Wcat bf16 (dead after kgemm)
#define PHK_OFF  104857600ull    // phi_k bf16, written in kphi (over dead WB)
#define WRFB_OFF 131072000ull    // 131,072 B Wrf bf16 (dead after kphi)
#define PKL_OFF  131072000ull    // 25,165,824 B (over dead WRFB)
#define VL_OFF   156237824ull    // 25,165,824 B
#define A1_OFF   0ull            // 33,554,432 B (over dead QBH/KBH)
#define DEN_OFF  181403648ull    // 819,200 B
#define SC_OFF   182222848ull    // 16 B scalars

__device__ __forceinline__ void gload16(const bf16_t* g, bf16_t* l) {
    __builtin_amdgcn_global_load_lds(
        (const __attribute__((address_space(1))) void*)g,
        (__attribute__((address_space(3))) void*)l, 16, 0, 0);
}

// ---------------- convert x -> bf16 ----------------
__global__ __launch_bounds__(256)
void kconv_x(const float* __restrict__ x, bf16_t* __restrict__ xb, int n4) {
    int i = blockIdx.x * blockDim.x + threadIdx.x;
    int stride = gridDim.x * blockDim.x;
    const f32x4* x4 = (const f32x4*)x;
    for (; i < n4; i += stride) {
        f32x4 v = x4[i];
        bf16_t* o = xb + 4*(size_t)i;
        o[0] = (bf16_t)v[0]; o[1] = (bf16_t)v[1];
        o[2] = (bf16_t)v[2]; o[3] = (bf16_t)v[3];
    }
}

// ---------------- convert Wq|Wk|Wv -> bf16 concatenated [3072][1024] ----------------
__global__ __launch_bounds__(256)
void kconv_w(const float* __restrict__ Wq, const float* __restrict__ Wk,
             const float* __restrict__ Wv, bf16_t* __restrict__ wb, int n4) {
    int i = blockIdx.x * blockDim.x + threadIdx.x;
    int stride = gridDim.x * blockDim.x;
    for (; i < n4; i += stride) {
        int f = i * 4;
        int row = f >> 10;
        int col = f & 1023;
        const float* src = (row < 1024) ? Wq : ((row < 2048) ? Wk : Wv);
        const f32x4 v = *(const f32x4*)(src + ((size_t)(row & 1023) << 10) + col);
        bf16_t* o = wb + (size_t)f;
        o[0] = (bf16_t)v[0]; o[1] = (bf16_t)v[1];
        o[2] = (bf16_t)v[2]; o[3] = (bf16_t)v[3];
    }
}

// ---------------- convert Wrf -> bf16 [16][64][64] ----------------
__global__ __launch_bounds__(256)
void kconv_wrf(const float* __restrict__ w, bf16_t* __restrict__ o, int n4) {
    int i = blockIdx.x * blockDim.x + threadIdx.x;
    if (i >= n4) return;
    f32x4 v = ((const f32x4*)w)[i];
    bf16_t* p = o + 4*(size_t)i;
    p[0] = (bf16_t)v[0]; p[1] = (bf16_t)v[1];
    p[2] = (bf16_t)v[2]; p[3] = (bf16_t)v[3];
}

// ---------------- fused QKV GEMM, LDS-staged (m97 structure) ----------------
// out[r][c]=sum_k x[r][k]*Wcat[c][k] + b[c]; q,k,v written bf16; ssq from fp32.
// 128x128 block tile, 4 waves 2x2 (64x64 each), BK=32, global_load_lds width 16,
// double-buffered LDS, one barrier per K-step.
__global__ __launch_bounds__(256)
void kgemm(const bf16_t* __restrict__ xb, const bf16_t* __restrict__ wb,
           const float* __restrict__ bq, const float* __restrict__ bk,
           const float* __restrict__ bv,
           bf16_t* __restrict__ qbh, bf16_t* __restrict__ kbh,
           bf16_t* __restrict__ vbh, float* __restrict__ ssq) {
    __shared__ bf16_t sA[2][128*32];
    __shared__ bf16_t sB[2][128*32];
    const int lane = threadIdx.x & 63;
    const int wid  = threadIdx.x >> 6;
    const int row0 = blockIdx.y * 128;
    const int col0 = blockIdx.x * 128;
    const int wr = (wid >> 1) * 64;
    const int wc = (wid & 1) * 64;
    const int ar = lane & 15;
    const int kg = lane >> 4;

    // staging: wave wid covers rows [wid*16, wid*16+16) and [64+wid*16, ...)
    const int srow = lane >> 2;
    const int scol = (lane & 3) * 8;
    const bf16_t* gA0 = xb + (size_t)(row0 + wid*16 + srow) * 1024 + scol;
    const bf16_t* gA1 = gA0 + (size_t)64 * 1024;
    const bf16_t* gB0 = wb + (size_t)(col0 + wid*16 + srow) * 1024 + scol;
    const bf16_t* gB1 = gB0 + (size_t)64 * 1024;
    const int lOffA0 = (wid*16) * 32;        // wave-uniform LDS element offsets
    const int lOffA1 = (64 + wid*16) * 32;

    f32x4 acc[4][4];
#pragma unroll
    for (int m = 0; m < 4; m++)
#pragma unroll
        for (int n = 0; n < 4; n++)
            acc[m][n] = (f32x4){0.f, 0.f, 0.f, 0.f};

    // prologue: stage k=0 into buffer 0
    gload16(gA0, &sA[0][lOffA0]);
    gload16(gA1, &sA[0][lOffA1]);
    gload16(gB0, &sB[0][lOffA0]);
    gload16(gB1, &sB[0][lOffA1]);

    for (int ks = 0; ks < 32; ks++) {
        const int p = ks & 1;
        __syncthreads();   // drains vmcnt: buffer p staged; all waves past compute(ks-1)
        if (ks + 1 < 32) {
            const int k = (ks + 1) * 32;
            gload16(gA0 + k, &sA[p^1][lOffA0]);
            gload16(gA1 + k, &sA[p^1][lOffA1]);
            gload16(gB0 + k, &sB[p^1][lOffA0]);
            gload16(gB1 + k, &sB[p^1][lOffA1]);
        }
        bf16x8 a[4], b[4];
#pragma unroll
        for (int rf = 0; rf < 4; rf++)
            a[rf] = *(const bf16x8*)&sA[p][(wr + rf*16 + ar)*32 + kg*8];
#pragma unroll
        for (int cf = 0; cf < 4; cf++)
            b[cf] = *(const bf16x8*)&sB[p][(wc + cf*16 + ar)*32 + kg*8];
#pragma unroll
        for (int rf = 0; rf < 4; rf++)
#pragma unroll
            for (int cf = 0; cf < 4; cf++)
                acc[rf][cf] = __builtin_amdgcn_mfma_f32_16x16x32_bf16(
                    a[rf], b[cf], acc[rf][cf], 0, 0, 0);
    }

    float s0 = 0.f, s1 = 0.f;
#pragma unroll
    for (int n = 0; n < 4; n++) {
        const int c = col0 + wc + n*16 + ar;
        const int which = c >> 10;           // uniform per fragment
        const int cc = c & 1023;
        const float bias = (which == 0 ? bq : (which == 1 ? bk : bv))[cc];
        bf16_t* ob = (which == 0 ? qbh : (which == 1 ? kbh : vbh));
#pragma unroll
        for (int m = 0; m < 4; m++) {
#pragma unroll
            for (int j = 0; j < 4; j++) {
                const int r = row0 + wr + m*16 + kg*4 + j;
                const float val = acc[m][n][j] + bias;
                ob[(size_t)r * 1024 + cc] = (bf16_t)val;
                if (which == 0) s0 += val * val;
                else if (which == 1) s1 += val * val;
            }
        }
    }
    for (int off = 32; off; off >>= 1) {
        s0 += __shfl_xor(s0, off);
        s1 += __shfl_xor(s1, off);
    }
    if (lane == 0) {
        if (s0 != 0.f) atomicAdd(ssq + 0, s0);
        if (s1 != 0.f) atomicAdd(ssq + 1, s1);
    }
}

// ---------------- finalize norms ----------------
__global__ void knorm(float* sc) {
    if (threadIdx.x == 0) {
        sc[2] = rsqrtf(sc[0]);
        sc[3] = rsqrtf(sc[1]);
    }
}

// ---------------- phi via MFMA: per (h, bs-tile); phi_q/phi_k bf16 + den ----------------
__global__ __launch_bounds__(256)
void kphi_mfma(const bf16_t* __restrict__ qbh, const bf16_t* __restrict__ kbh,
               const bf16_t* __restrict__ wrfb, const float* __restrict__ sc,
               bf16_t* __restrict__ phqb, bf16_t* __restrict__ phkb,
               float* __restrict__ den) {
    const int lane = threadIdx.x & 63;
    const int wid  = threadIdx.x >> 6;
    const int h    = blockIdx.y;
    const int bs0  = blockIdx.x * 256 + wid * 64;
    const int ar = lane & 15;
    const int kg = lane >> 4;

    bf16x8 bfr[4][2];
#pragma unroll
    for (int cf = 0; cf < 4; cf++)
#pragma unroll
        for (int ks = 0; ks < 2; ks++)
            bfr[cf][ks] = *(const bf16x8*)(wrfb +
                ((size_t)(h * 64 + cf * 16 + ar) * 64 + ks * 32 + kg * 8));

    f32x4 aq[4][4], ak[4][4];
#pragma unroll
    for (int rf = 0; rf < 4; rf++)
#pragma unroll
        for (int cf = 0; cf < 4; cf++) {
            aq[rf][cf] = (f32x4){0.f, 0.f, 0.f, 0.f};
            ak[rf][cf] = (f32x4){0.f, 0.f, 0.f, 0.f};
        }

#pragma unroll
    for (int rf = 0; rf < 4; rf++) {
        const size_t urow = ((size_t)(bs0 + rf*16 + ar) * 16 + h) * 64 + kg * 8;
        const bf16x8 a0 = *(const bf16x8*)(qbh + urow);
        const bf16x8 a1 = *(const bf16x8*)(qbh + urow + 32);
        const bf16x8 c0 = *(const bf16x8*)(kbh + urow);
        const bf16x8 c1 = *(const bf16x8*)(kbh + urow + 32);
#pragma unroll
        for (int cf = 0; cf < 4; cf++) {
            aq[rf][cf] = __builtin_amdgcn_mfma_f32_16x16x32_bf16(a0, bfr[cf][0], aq[rf][cf], 0, 0, 0);
            aq[rf][cf] = __builtin_amdgcn_mfma_f32_16x16x32_bf16(a1, bfr[cf][1], aq[rf][cf], 0, 0, 0);
            ak[rf][cf] = __builtin_amdgcn_mfma_f32_16x16x32_bf16(c0, bfr[cf][0], ak[rf][cf], 0, 0, 0);
            ak[rf][cf] = __builtin_amdgcn_mfma_f32_16x16x32_bf16(c1, bfr[cf][1], ak[rf][cf], 0, 0, 0);
        }
    }

    const float qs = sc[2];
    const float ksc = sc[3];
    const float CPHI = 0.009477041545882225f;  // exp(-0.5)/64

#pragma unroll
    for (int rf = 0; rf < 4; rf++) {
        float t[4] = {0.f, 0.f, 0.f, 0.f};
#pragma unroll
        for (int cf = 0; cf < 4; cf++) {
#pragma unroll
            for (int j = 0; j < 4; j++) {
                const float vq = expf(aq[rf][cf][j] * qs) * CPHI;
                const float vk = expf(ak[rf][cf][j] * ksc) * CPHI;
                const int bs = bs0 + rf*16 + kg*4 + j;
                const size_t o = ((size_t)bs * 16 + h) * 64 + cf * 16 + ar;
                phqb[o] = (bf16_t)vq;
                phkb[o] = (bf16_t)vk;
                t[j] += vq * vk;
            }
        }
#pragma unroll
        for (int j = 0; j < 4; j++) {
            float tt = t[j];
            tt += __shfl_xor(tt, 1);
            tt += __shfl_xor(tt, 2);
            tt += __shfl_xor(tt, 4);
            tt += __shfl_xor(tt, 8);
            if (ar == 0) {
                const int bs = bs0 + rf*16 + kg*4 + j;
                den[bs * 16 + h] = tt;
            }
        }
    }
}

// ---------------- pkl[b,h,l,m] = sum_s phi_k * E ; vl[b,h,l,d] = sum_s v * F ----------------
__global__ __launch_bounds__(256)
void kpklvl(const bf16_t* __restrict__ phk, const bf16_t* __restrict__ vbh,
            const float* __restrict__ E, const float* __restrict__ F,
            float* __restrict__ pkl, float* __restrict__ vl) {
    __shared__ float sph[SQ * 64];
    __shared__ float svv[SQ * 64];
    const int bh = blockIdx.x;            // b*16 + h
    const int b = bh >> 4, h = bh & 15;

    for (int t = threadIdx.x; t < SQ * 64; t += 256) {
        const int s = t >> 6, m = t & 63;
        const size_t g = ((size_t)(b * SQ + s) * 16 + h) * 64 + m;
        sph[t] = (float)phk[g];
        svv[t] = (float)vbh[g];
    }
    __syncthreads();

    for (int t = threadIdx.x; t < LL * 64; t += 256) {
        const int l = t >> 6, m = t & 63;
        float a1 = 0.f, a2 = 0.f;
        for (int s = 0; s < SQ; s++) {
            const float e = E[s * LL + l];
            const float f = F[s * LL + l];
            a1 += sph[s * 64 + m] * e;
            a2 += svv[s * 64 + m] * f;
        }
        const size_t o = ((size_t)bh * LL + l) * 64 + m;
        pkl[o] = a1;
        vl[o] = a2;
    }
}

// ---------------- A1[b,h,m,d] = sum_l pkl[l][m] * vl[l][d] ----------------
__global__ __launch_bounds__(256)
void ka1(const float* __restrict__ pkl, const float* __restrict__ vl,
         float* __restrict__ A1) {
    __shared__ float sp[LL * 64];
    __shared__ float sv[LL * 64];
    const int bh = blockIdx.x;
    for (int t = threadIdx.x; t < LL * 64; t += 256) {
        const size_t g = (size_t)bh * LL * 64 + t;
        sp[t] = pkl[g];
        sv[t] = vl[g];
    }
    __syncthreads();

    const int m = threadIdx.x >> 2;
    const int dg = (threadIdx.x & 3) * 16;
    float acc[16];
#pragma unroll
    for (int j = 0; j < 16; j++) acc[j] = 0.f;

    for (int l = 0; l < LL; l++) {
        const float a = sp[l * 64 + m];
        const float* vrow = &sv[l * 64 + dg];
#pragma unroll
        for (int j = 0; j < 16; j++) acc[j] += a * vrow[j];
    }
    float* o = A1 + (size_t)bh * 4096 + (size_t)m * 64 + dg;
#pragma unroll
    for (int j = 0; j < 16; j++) o[j] = acc[j];
}

// ---------------- final: out[unit*64+d] = (sum_m phi_q[m]*A1[m][d]) / den ----------------
__global__ __launch_bounds__(256)
void kfinal(const bf16_t* __restrict__ phq, const float* __restrict__ A1,
            const float* __restrict__ den, float* __restrict__ out) {
    const int unit = blockIdx.x * 4 + (threadIdx.x >> 6);
    const int lane = threadIdx.x & 63;
    const int h = unit & 15;
    const int b = unit / (SQ * 16);
    const int bh = b * 16 + h;

    const float* a = A1 + (size_t)bh * 4096;
    const bf16_t* p = phq + (size_t)unit * 64;
    float accv = 0.f;
#pragma unroll 4
    for (int m = 0; m < 64; m++) accv += (float)p[m] * a[(size_t)m * 64 + lane];
    out[(size_t)unit * 64 + lane] = accv / den[unit];
}

extern "C" void kernel_launch(void* const* d_in, const int* in_sizes, int n_in,
                              void* d_out, int out_size, void* d_ws, size_t ws_size,
                              hipStream_t stream) {
    const float* x   = (const float*)d_in[0];
    const float* Wq  = (const float*)d_in[1];
    const float* bq  = (const float*)d_in[2];
    const float* Wk  = (const float*)d_in[3];
    const float* bk  = (const float*)d_in[4];
    const float* Wv  = (const float*)d_in[5];
    const float* bv  = (const float*)d_in[6];
    const float* Wrf = (const float*)d_in[7];
    const float* E   = (const float*)d_in[8];
    const float* F   = (const float*)d_in[9];
    float* out = (float*)d_out;

    char* ws = (char*)d_ws;
    bf16_t* qbh  = (bf16_t*)(ws + QBH_OFF);
    bf16_t* kbh  = (bf16_t*)(ws + KBH_OFF);
    bf16_t* vbh  = (bf16_t*)(ws + VBH_OFF);
    bf16_t* xb   = (bf16_t*)(ws + XB_OFF);
    bf16_t* phqb = (bf16_t*)(ws + PHQ_OFF);
    bf16_t* wb   = (bf16_t*)(ws + WB_OFF);
    bf16_t* phkb = (bf16_t*)(ws + PHK_OFF);
    bf16_t* wrfb = (bf16_t*)(ws + WRFB_OFF);
    float*  pkl  = (float*)(ws + PKL_OFF);
    float*  vl   = (float*)(ws + VL_OFF);
    float*  A1   = (float*)(ws + A1_OFF);
    float*  den  = (float*)(ws + DEN_OFF);
    float*  sc   = (float*)(ws + SC_OFF);

    hipMemsetAsync(sc, 0, 16, stream);
    kconv_x<<<2048, 256, 0, stream>>>(x, xb, BS * 1024 / 4);
    kconv_w<<<1024, 256, 0, stream>>>(Wq, Wk, Wv, wb, 3 * 1024 * 1024 / 4);
    kconv_wrf<<<64, 256, 0, stream>>>(Wrf, wrfb, HH * MM * DD / 4);

    dim3 ggrid(24, 100);   // 3072/128 cols x 12800/128 rows
    kgemm<<<ggrid, 256, 0, stream>>>(xb, wb, bq, bk, bv, qbh, kbh, vbh, sc);

    knorm<<<1, 64, 0, stream>>>(sc);
    dim3 pgrid(50, 16);    // 12800/256 bs-tiles x 16 heads
    kphi_mfma<<<pgrid, 256, 0, stream>>>(qbh, kbh, wrfb, sc, phqb, phkb, den);
    kpklvl<<<BQ * HH, 256, 0, stream>>>(phkb, vbh, E, F, pkl, vl);
    ka1<<<BQ * HH, 256, 0, stream>>>(pkl, vl, A1);
    kfinal<<<UNITS / 4, 256, 0, stream>>>(phqb, A1, den, out);
}

// Round 4
// 409.519 us; speedup vs baseline: 3.2551x; 1.4635x over previous
//
#include <hip/hip_runtime.h>
#include <math.h>

// Problem constants
#define BQ 128
#define SQ 100
#define EDIM 1024
#define HH 16
#define LL 48
#define DD 64
#define MM 64
#define BS (BQ*SQ)        // 12800 rows
#define UNITS (BS*HH)     // 204800 (b,s,h) units

typedef __bf16 bf16_t;
typedef bf16_t bf16x8 __attribute__((ext_vector_type(8)));
typedef float f32x4 __attribute__((ext_vector_type(4)));

// Workspace byte offsets (peak ~182.2 MB)
#define QBH_OFF  0ull            // 26,214,400 B q bf16 (dead after kphi)
#define KBH_OFF  26214400ull     // 26,214,400 B k bf16 (dead after kphi)
#define VBH_OFF  52428800ull     // 26,214,400 B v bf16 (dead after kpklvl)
#define XB_OFF   78643200ull     // 26,214,400 B x bf16 (dead after kgemm)
#define PHQ_OFF  78643200ull     // phi_q/den bf16 (over dead XB)
#define WB_OFF   104857600ull    // 6,291,456 B Wcat bf16 (dead after kgemm)
#define PHK_OFF  104857600ull    // phi_k bf16 (over dead WB)
#define WRFB_OFF 131072000ull    // 131,072 B Wrf bf16 (dead after kphi)
#define PKL_OFF  131072000ull    // 25,165,824 B (over dead WRFB)
#define VL_OFF   156237824ull    // 25,165,824 B
#define A1T_OFF  0ull            // 16,777,216 B bf16 A1^T (over dead QBH)
#define SC_OFF   182222848ull    // 16 B scalars

__device__ __forceinline__ void gload16(const bf16_t* g, bf16_t* l) {
    __builtin_amdgcn_global_load_lds(
        (const __attribute__((address_space(1))) void*)g,
        (__attribute__((address_space(3))) void*)l, 16, 0, 0);
}

// ---------------- convert x -> bf16 ----------------
__global__ __launch_bounds__(256)
void kconv_x(const float* __restrict__ x, bf16_t* __restrict__ xb, int n4) {
    int i = blockIdx.x * blockDim.x + threadIdx.x;
    int stride = gridDim.x * blockDim.x;
    const f32x4* x4 = (const f32x4*)x;
    for (; i < n4; i += stride) {
        f32x4 v = x4[i];
        bf16_t* o = xb + 4*(size_t)i;
        o[0] = (bf16_t)v[0]; o[1] = (bf16_t)v[1];
        o[2] = (bf16_t)v[2]; o[3] = (bf16_t)v[3];
    }
}

// ---------------- convert Wq|Wk|Wv -> bf16 concatenated [3072][1024] ----------------
__global__ __launch_bounds__(256)
void kconv_w(const float* __restrict__ Wq, const float* __restrict__ Wk,
             const float* __restrict__ Wv, bf16_t* __restrict__ wb, int n4) {
    int i = blockIdx.x * blockDim.x + threadIdx.x;
    int stride = gridDim.x * blockDim.x;
    for (; i < n4; i += stride) {
        int f = i * 4;
        int row = f >> 10;
        int col = f & 1023;
        const float* src = (row < 1024) ? Wq : ((row < 2048) ? Wk : Wv);
        const f32x4 v = *(const f32x4*)(src + ((size_t)(row & 1023) << 10) + col);
        bf16_t* o = wb + (size_t)f;
        o[0] = (bf16_t)v[0]; o[1] = (bf16_t)v[1];
        o[2] = (bf16_t)v[2]; o[3] = (bf16_t)v[3];
    }
}

// ---------------- convert Wrf -> bf16 [16][64][64] ----------------
__global__ __launch_bounds__(256)
void kconv_wrf(const float* __restrict__ w, bf16_t* __restrict__ o, int n4) {
    int i = blockIdx.x * blockDim.x + threadIdx.x;
    if (i >= n4) return;
    f32x4 v = ((const f32x4*)w)[i];
    bf16_t* p = o + 4*(size_t)i;
    p[0] = (bf16_t)v[0]; p[1] = (bf16_t)v[1];
    p[2] = (bf16_t)v[2]; p[3] = (bf16_t)v[3];
}

// ---------------- fused QKV GEMM, LDS-staged (m97 structure) ----------------
__global__ __launch_bounds__(256)
void kgemm(const bf16_t* __restrict__ xb, const bf16_t* __restrict__ wb,
           const float* __restrict__ bq, const float* __restrict__ bk,
           const float* __restrict__ bv,
           bf16_t* __restrict__ qbh, bf16_t* __restrict__ kbh,
           bf16_t* __restrict__ vbh, float* __restrict__ ssq) {
    __shared__ bf16_t sA[2][128*32];
    __shared__ bf16_t sB[2][128*32];
    const int lane = threadIdx.x & 63;
    const int wid  = threadIdx.x >> 6;
    const int row0 = blockIdx.y * 128;
    const int col0 = blockIdx.x * 128;
    const int wr = (wid >> 1) * 64;
    const int wc = (wid & 1) * 64;
    const int ar = lane & 15;
    const int kg = lane >> 4;

    const int srow = lane >> 2;
    const int scol = (lane & 3) * 8;
    const bf16_t* gA0 = xb + (size_t)(row0 + wid*16 + srow) * 1024 + scol;
    const bf16_t* gA1 = gA0 + (size_t)64 * 1024;
    const bf16_t* gB0 = wb + (size_t)(col0 + wid*16 + srow) * 1024 + scol;
    const bf16_t* gB1 = gB0 + (size_t)64 * 1024;
    const int lOffA0 = (wid*16) * 32;
    const int lOffA1 = (64 + wid*16) * 32;

    f32x4 acc[4][4];
#pragma unroll
    for (int m = 0; m < 4; m++)
#pragma unroll
        for (int n = 0; n < 4; n++)
            acc[m][n] = (f32x4){0.f, 0.f, 0.f, 0.f};

    gload16(gA0, &sA[0][lOffA0]);
    gload16(gA1, &sA[0][lOffA1]);
    gload16(gB0, &sB[0][lOffA0]);
    gload16(gB1, &sB[0][lOffA1]);

    for (int ks = 0; ks < 32; ks++) {
        const int p = ks & 1;
        __syncthreads();
        if (ks + 1 < 32) {
            const int k = (ks + 1) * 32;
            gload16(gA0 + k, &sA[p^1][lOffA0]);
            gload16(gA1 + k, &sA[p^1][lOffA1]);
            gload16(gB0 + k, &sB[p^1][lOffA0]);
            gload16(gB1 + k, &sB[p^1][lOffA1]);
        }
        bf16x8 a[4], b[4];
#pragma unroll
        for (int rf = 0; rf < 4; rf++)
            a[rf] = *(const bf16x8*)&sA[p][(wr + rf*16 + ar)*32 + kg*8];
#pragma unroll
        for (int cf = 0; cf < 4; cf++)
            b[cf] = *(const bf16x8*)&sB[p][(wc + cf*16 + ar)*32 + kg*8];
#pragma unroll
        for (int rf = 0; rf < 4; rf++)
#pragma unroll
            for (int cf = 0; cf < 4; cf++)
                acc[rf][cf] = __builtin_amdgcn_mfma_f32_16x16x32_bf16(
                    a[rf], b[cf], acc[rf][cf], 0, 0, 0);
    }

    float s0 = 0.f, s1 = 0.f;
#pragma unroll
    for (int n = 0; n < 4; n++) {
        const int c = col0 + wc + n*16 + ar;
        const int which = c >> 10;
        const int cc = c & 1023;
        const float bias = (which == 0 ? bq : (which == 1 ? bk : bv))[cc];
        bf16_t* ob = (which == 0 ? qbh : (which == 1 ? kbh : vbh));
#pragma unroll
        for (int m = 0; m < 4; m++) {
#pragma unroll
            for (int j = 0; j < 4; j++) {
                const int r = row0 + wr + m*16 + kg*4 + j;
                const float val = acc[m][n][j] + bias;
                ob[(size_t)r * 1024 + cc] = (bf16_t)val;
                if (which == 0) s0 += val * val;
                else if (which == 1) s1 += val * val;
            }
        }
    }
    for (int off = 32; off; off >>= 1) {
        s0 += __shfl_xor(s0, off);
        s1 += __shfl_xor(s1, off);
    }
    if (lane == 0) {
        if (s0 != 0.f) atomicAdd(ssq + 0, s0);
        if (s1 != 0.f) atomicAdd(ssq + 1, s1);
    }
}

// ---------------- finalize norms ----------------
__global__ void knorm(float* sc) {
    if (threadIdx.x == 0) {
        sc[2] = rsqrtf(sc[0]);
        sc[3] = rsqrtf(sc[1]);
    }
}

// ---------------- phi via MFMA; phi_q pre-divided by den ----------------
__global__ __launch_bounds__(256)
void kphi_mfma(const bf16_t* __restrict__ qbh, const bf16_t* __restrict__ kbh,
               const bf16_t* __restrict__ wrfb, const float* __restrict__ sc,
               bf16_t* __restrict__ phqb, bf16_t* __restrict__ phkb) {
    const int lane = threadIdx.x & 63;
    const int wid  = threadIdx.x >> 6;
    const int h    = blockIdx.y;
    const int bs0  = blockIdx.x * 256 + wid * 64;
    const int ar = lane & 15;
    const int kg = lane >> 4;

    bf16x8 bfr[4][2];
#pragma unroll
    for (int cf = 0; cf < 4; cf++)
#pragma unroll
        for (int ks = 0; ks < 2; ks++)
            bfr[cf][ks] = *(const bf16x8*)(wrfb +
                ((size_t)(h * 64 + cf * 16 + ar) * 64 + ks * 32 + kg * 8));

    f32x4 aq[4][4], ak[4][4];
#pragma unroll
    for (int rf = 0; rf < 4; rf++)
#pragma unroll
        for (int cf = 0; cf < 4; cf++) {
            aq[rf][cf] = (f32x4){0.f, 0.f, 0.f, 0.f};
            ak[rf][cf] = (f32x4){0.f, 0.f, 0.f, 0.f};
        }

#pragma unroll
    for (int rf = 0; rf < 4; rf++) {
        const size_t urow = ((size_t)(bs0 + rf*16 + ar) * 16 + h) * 64 + kg * 8;
        const bf16x8 a0 = *(const bf16x8*)(qbh + urow);
        const bf16x8 a1 = *(const bf16x8*)(qbh + urow + 32);
        const bf16x8 c0 = *(const bf16x8*)(kbh + urow);
        const bf16x8 c1 = *(const bf16x8*)(kbh + urow + 32);
#pragma unroll
        for (int cf = 0; cf < 4; cf++) {
            aq[rf][cf] = __builtin_amdgcn_mfma_f32_16x16x32_bf16(a0, bfr[cf][0], aq[rf][cf], 0, 0, 0);
            aq[rf][cf] = __builtin_amdgcn_mfma_f32_16x16x32_bf16(a1, bfr[cf][1], aq[rf][cf], 0, 0, 0);
            ak[rf][cf] = __builtin_amdgcn_mfma_f32_16x16x32_bf16(c0, bfr[cf][0], ak[rf][cf], 0, 0, 0);
            ak[rf][cf] = __builtin_amdgcn_mfma_f32_16x16x32_bf16(c1, bfr[cf][1], ak[rf][cf], 0, 0, 0);
        }
    }

    const float qs = sc[2];
    const float ksc = sc[3];
    const float CPHI = 0.009477041545882225f;  // exp(-0.5)/64

#pragma unroll
    for (int rf = 0; rf < 4; rf++) {
        float vq[4][4], vk[4][4];
        float t[4] = {0.f, 0.f, 0.f, 0.f};
#pragma unroll
        for (int cf = 0; cf < 4; cf++) {
#pragma unroll
            for (int j = 0; j < 4; j++) {
                const float q_ = expf(aq[rf][cf][j] * qs) * CPHI;
                const float k_ = expf(ak[rf][cf][j] * ksc) * CPHI;
                vq[cf][j] = q_;
                vk[cf][j] = k_;
                t[j] += q_ * k_;
            }
        }
#pragma unroll
        for (int j = 0; j < 4; j++) {
            t[j] += __shfl_xor(t[j], 1);
            t[j] += __shfl_xor(t[j], 2);
            t[j] += __shfl_xor(t[j], 4);
            t[j] += __shfl_xor(t[j], 8);
            t[j] = 1.0f / t[j];          // all 16 lanes of the group hold den
        }
#pragma unroll
        for (int cf = 0; cf < 4; cf++) {
#pragma unroll
            for (int j = 0; j < 4; j++) {
                const int bs = bs0 + rf*16 + kg*4 + j;
                const size_t o = ((size_t)bs * 16 + h) * 64 + cf * 16 + ar;
                phqb[o] = (bf16_t)(vq[cf][j] * t[j]);   // phi_q / den
                phkb[o] = (bf16_t)vk[cf][j];
            }
        }
    }
}

// ---------------- pkl[b,h,l,m] = sum_s phi_k * E ; vl[b,h,l,d] = sum_s v * F ----------------
__global__ __launch_bounds__(256)
void kpklvl(const bf16_t* __restrict__ phk, const bf16_t* __restrict__ vbh,
            const float* __restrict__ E, const float* __restrict__ F,
            float* __restrict__ pkl, float* __restrict__ vl) {
    __shared__ float sph[SQ * 64];
    __shared__ float svv[SQ * 64];
    const int bh = blockIdx.x;            // b*16 + h
    const int b = bh >> 4, h = bh & 15;

    for (int t = threadIdx.x; t < SQ * 64; t += 256) {
        const int s = t >> 6, m = t & 63;
        const size_t g = ((size_t)(b * SQ + s) * 16 + h) * 64 + m;
        sph[t] = (float)phk[g];
        svv[t] = (float)vbh[g];
    }
    __syncthreads();

    for (int t = threadIdx.x; t < LL * 64; t += 256) {
        const int l = t >> 6, m = t & 63;
        float a1 = 0.f, a2 = 0.f;
        for (int s = 0; s < SQ; s++) {
            const float e = E[s * LL + l];
            const float f = F[s * LL + l];
            a1 += sph[s * 64 + m] * e;
            a2 += svv[s * 64 + m] * f;
        }
        const size_t o = ((size_t)bh * LL + l) * 64 + m;
        pkl[o] = a1;
        vl[o] = a2;
    }
}

// ---------------- A1t[b,h,d,m] = sum_l pkl[l][m] * vl[l][d]  (bf16) ----------------
__global__ __launch_bounds__(256)
void ka1(const float* __restrict__ pkl, const float* __restrict__ vl,
         bf16_t* __restrict__ A1t) {
    __shared__ float sp[LL * 64];
    __shared__ float sv[LL * 64];
    const int bh = blockIdx.x;
    for (int t = threadIdx.x; t < LL * 64; t += 256) {
        const size_t g = (size_t)bh * LL * 64 + t;
        sp[t] = pkl[g];
        sv[t] = vl[g];
    }
    __syncthreads();

    const int d  = threadIdx.x >> 2;
    const int mg = (threadIdx.x & 3) * 16;
    float acc[16];
#pragma unroll
    for (int j = 0; j < 16; j++) acc[j] = 0.f;

    for (int l = 0; l < LL; l++) {
        const float b = sv[l * 64 + d];
        const float* prow = &sp[l * 64 + mg];
#pragma unroll
        for (int j = 0; j < 16; j++) acc[j] += b * prow[j];
    }
    bf16_t* o = A1t + (size_t)bh * 4096 + (size_t)d * 64 + mg;
#pragma unroll
    for (int j = 0; j < 16; j++) o[j] = (bf16_t)acc[j];
}

// ---------------- final via MFMA: out[s][d] = sum_m phiq_scaled[s][m] * A1t[d][m] ----------------
// block per bh, 2 waves; rows (s) tiled 8x16 (covers 128 >= 100, clamp/mask)
__global__ __launch_bounds__(128)
void kfinal(const bf16_t* __restrict__ phq, const bf16_t* __restrict__ A1t,
            float* __restrict__ out) {
    const int lane = threadIdx.x & 63;
    const int wid  = threadIdx.x >> 6;
    const int bh = blockIdx.x;
    const int b = bh >> 4, h = bh & 15;
    const int ar = lane & 15;
    const int kg = lane >> 4;

    // B fragments: A1t[d = cf*16+ar][m = ks*32+kg*8+e]
    bf16x8 bfr[4][2];
    const bf16_t* abase = A1t + (size_t)bh * 4096;
#pragma unroll
    for (int cf = 0; cf < 4; cf++)
#pragma unroll
        for (int ks = 0; ks < 2; ks++)
            bfr[cf][ks] = *(const bf16x8*)(abase + (size_t)(cf*16 + ar) * 64 + ks*32 + kg*8);

    f32x4 acc[4][4];
#pragma unroll
    for (int rf = 0; rf < 4; rf++)
#pragma unroll
        for (int cf = 0; cf < 4; cf++)
            acc[rf][cf] = (f32x4){0.f, 0.f, 0.f, 0.f};

#pragma unroll
    for (int rf = 0; rf < 4; rf++) {
        const int rfg = wid * 4 + rf;                 // 0..7
        int s = rfg * 16 + ar;
        s = s > 99 ? 99 : s;                          // clamp loads
        const bf16_t* prow = phq + ((size_t)(b * SQ + s) * 16 + h) * 64 + kg * 8;
        const bf16x8 a0 = *(const bf16x8*)prow;
        const bf16x8 a1 = *(const bf16x8*)(prow + 32);
#pragma unroll
        for (int cf = 0; cf < 4; cf++) {
            acc[rf][cf] = __builtin_amdgcn_mfma_f32_16x16x32_bf16(a0, bfr[cf][0], acc[rf][cf], 0, 0, 0);
            acc[rf][cf] = __builtin_amdgcn_mfma_f32_16x16x32_bf16(a1, bfr[cf][1], acc[rf][cf], 0, 0, 0);
        }
    }

#pragma unroll
    for (int rf = 0; rf < 4; rf++) {
        const int rfg = wid * 4 + rf;
#pragma unroll
        for (int cf = 0; cf < 4; cf++) {
#pragma unroll
            for (int j = 0; j < 4; j++) {
                const int s = rfg * 16 + kg * 4 + j;
                if (s < SQ) {
                    out[((size_t)(b * SQ + s) * 16 + h) * 64 + cf * 16 + ar] = acc[rf][cf][j];
                }
            }
        }
    }
}

extern "C" void kernel_launch(void* const* d_in, const int* in_sizes, int n_in,
                              void* d_out, int out_size, void* d_ws, size_t ws_size,
                              hipStream_t stream) {
    const float* x   = (const float*)d_in[0];
    const float* Wq  = (const float*)d_in[1];
    const float* bq  = (const float*)d_in[2];
    const float* Wk  = (const float*)d_in[3];
    const float* bk  = (const float*)d_in[4];
    const float* Wv  = (const float*)d_in[5];
    const float* bv  = (const float*)d_in[6];
    const float* Wrf = (const float*)d_in[7];
    const float* E   = (const float*)d_in[8];
    const float* F   = (const float*)d_in[9];
    float* out = (float*)d_out;

    char* ws = (char*)d_ws;
    bf16_t* qbh  = (bf16_t*)(ws + QBH_OFF);
    bf16_t* kbh  = (bf16_t*)(ws + KBH_OFF);
    bf16_t* vbh  = (bf16_t*)(ws + VBH_OFF);
    bf16_t* xb   = (bf16_t*)(ws + XB_OFF);
    bf16_t* phqb = (bf16_t*)(ws + PHQ_OFF);
    bf16_t* wb   = (bf16_t*)(ws + WB_OFF);
    bf16_t* phkb = (bf16_t*)(ws + PHK_OFF);
    bf16_t* wrfb = (bf16_t*)(ws + WRFB_OFF);
    float*  pkl  = (float*)(ws + PKL_OFF);
    float*  vl   = (float*)(ws + VL_OFF);
    bf16_t* A1t  = (bf16_t*)(ws + A1T_OFF);
    float*  sc   = (float*)(ws + SC_OFF);

    hipMemsetAsync(sc, 0, 16, stream);
    kconv_x<<<2048, 256, 0, stream>>>(x, xb, BS * 1024 / 4);
    kconv_w<<<1024, 256, 0, stream>>>(Wq, Wk, Wv, wb, 3 * 1024 * 1024 / 4);
    kconv_wrf<<<64, 256, 0, stream>>>(Wrf, wrfb, HH * MM * DD / 4);

    dim3 ggrid(24, 100);   // 3072/128 cols x 12800/128 rows
    kgemm<<<ggrid, 256, 0, stream>>>(xb, wb, bq, bk, bv, qbh, kbh, vbh, sc);

    knorm<<<1, 64, 0, stream>>>(sc);
    dim3 pgrid(50, 16);    // 12800/256 bs-tiles x 16 heads
    kphi_mfma<<<pgrid, 256, 0, stream>>>(qbh, kbh, wrfb, sc, phqb, phkb);
    kpklvl<<<BQ * HH, 256, 0, stream>>>(phkb, vbh, E, F, pkl, vl);
    ka1<<<BQ * HH, 256, 0, stream>>>(pkl, vl, A1t);
    kfinal<<<BQ * HH, 128, 0, stream>>>(phqb, A1t, out);
}

// Round 5
// 319.688 us; speedup vs baseline: 4.1698x; 1.2810x over previous
//
#include <hip/hip_runtime.h>
#include <math.h>

// Problem constants
#define BQ 128
#define SQ 100
#define HH 16
#define LL 48
#define BS (BQ*SQ)        // 12800 rows

typedef __bf16 bf16_t;
typedef bf16_t bf16x8 __attribute__((ext_vector_type(8)));
typedef float f32x4 __attribute__((ext_vector_type(4)));

// Workspace byte offsets (peak ~197.3 MB)
#define QBH_OFF  0ull            // 26,214,400 q bf16 [bs][1024]      (dead after kphi)
#define KBH_OFF  26214400ull     // 26,214,400 k bf16                  (dead after kphi)
#define VT_OFF   52428800ull     // 33,554,432 v^T bf16 [bh][64][128]  (dead after kw)
#define XB_OFF   85983232ull     // 26,214,400 x bf16                  (dead after kgemm)
#define PHQ_OFF  85983232ull     // phi_q/den bf16 [bh][100][64] (over dead XB)
#define WB_OFF   112197632ull    // 6,291,456 Wcat bf16                (dead after kgemm)
#define WRFB_OFF 118489088ull    // 131,072 Wrf bf16                   (dead after kphi)
#define G_OFF    118620160ull    // 28,672 G bf16 [112][128]           (dead after kw)
#define PHK_OFF  118648832ull    // 26,214,400 phi_k bf16 [bh][100][64] (dead after kP)
#define P_OFF    144863232ull    // 52,428,800 P bf16 [bh][100][128]   (dead after knum)
#define WT_OFF   0ull            // 33,554,432 W^T bf16 [bh][64][128] (over dead QBH/KBH)
#define SC_OFF   197292032ull    // 16 B scalars

__device__ __forceinline__ void gload16(const bf16_t* g, bf16_t* l) {
    __builtin_amdgcn_global_load_lds(
        (const __attribute__((address_space(1))) void*)g,
        (__attribute__((address_space(3))) void*)l, 16, 0, 0);
}

// ---------------- convert x -> bf16 ----------------
__global__ __launch_bounds__(256)
void kconv_x(const float* __restrict__ x, bf16_t* __restrict__ xb, int n4) {
    int i = blockIdx.x * blockDim.x + threadIdx.x;
    int stride = gridDim.x * blockDim.x;
    const f32x4* x4 = (const f32x4*)x;
    for (; i < n4; i += stride) {
        f32x4 v = x4[i];
        bf16_t* o = xb + 4*(size_t)i;
        o[0] = (bf16_t)v[0]; o[1] = (bf16_t)v[1];
        o[2] = (bf16_t)v[2]; o[3] = (bf16_t)v[3];
    }
}

// ---------------- convert Wq|Wk|Wv -> bf16 concatenated [3072][1024] ----------------
__global__ __launch_bounds__(256)
void kconv_w(const float* __restrict__ Wq, const float* __restrict__ Wk,
             const float* __restrict__ Wv, bf16_t* __restrict__ wb, int n4) {
    int i = blockIdx.x * blockDim.x + threadIdx.x;
    int stride = gridDim.x * blockDim.x;
    for (; i < n4; i += stride) {
        int f = i * 4;
        int row = f >> 10;
        int col = f & 1023;
        const float* src = (row < 1024) ? Wq : ((row < 2048) ? Wk : Wv);
        const f32x4 v = *(const f32x4*)(src + ((size_t)(row & 1023) << 10) + col);
        bf16_t* o = wb + (size_t)f;
        o[0] = (bf16_t)v[0]; o[1] = (bf16_t)v[1];
        o[2] = (bf16_t)v[2]; o[3] = (bf16_t)v[3];
    }
}

// ---------------- convert Wrf -> bf16 [16][64][64] ----------------
__global__ __launch_bounds__(256)
void kconv_wrf(const float* __restrict__ w, bf16_t* __restrict__ o, int n4) {
    int i = blockIdx.x * blockDim.x + threadIdx.x;
    if (i >= n4) return;
    f32x4 v = ((const f32x4*)w)[i];
    bf16_t* p = o + 4*(size_t)i;
    p[0] = (bf16_t)v[0]; p[1] = (bf16_t)v[1];
    p[2] = (bf16_t)v[2]; p[3] = (bf16_t)v[3];
}

// ---------------- G[s][t] = sum_l E[s][l]*F[t][l], zero-padded to [112][128] ----------------
__global__ __launch_bounds__(256)
void kG(const float* __restrict__ E, const float* __restrict__ F,
        bf16_t* __restrict__ G) {
    const int idx = blockIdx.x * 256 + threadIdx.x;   // 56*256 = 14336 = 112*128
    const int s = idx >> 7, t = idx & 127;
    float acc = 0.f;
    if (s < 100 && t < 100) {
#pragma unroll
        for (int l = 0; l < LL; l++) acc += E[s*LL+l] * F[t*LL+l];
    }
    G[idx] = (bf16_t)acc;
}

// ---------------- fused QKV GEMM, LDS-staged + XOR swizzle ----------------
// q,k -> bf16 [bs][1024]; v -> bf16 transposed [bh][d][s] (vt, pad pre-zeroed)
__global__ __launch_bounds__(256)
void kgemm(const bf16_t* __restrict__ xb, const bf16_t* __restrict__ wb,
           const float* __restrict__ bq, const float* __restrict__ bk,
           const float* __restrict__ bv,
           bf16_t* __restrict__ qbh, bf16_t* __restrict__ kbh,
           bf16_t* __restrict__ vt, float* __restrict__ ssq) {
    __shared__ bf16_t sA[2][128*32];
    __shared__ bf16_t sB[2][128*32];
    const int lane = threadIdx.x & 63;
    const int wid  = threadIdx.x >> 6;
    const int row0 = blockIdx.y * 128;
    const int col0 = blockIdx.x * 128;
    const int wr = (wid >> 1) * 64;
    const int wc = (wid & 1) * 64;
    const int ar = lane & 15;
    const int kg = lane >> 4;

    // staging: linear LDS dest, pre-swizzled global source slot
    const int srow = lane >> 2;
    const int sslot = (lane & 3) ^ ((lane >> 3) & 3);
    const int scol = sslot * 8;
    const bf16_t* gA0 = xb + (size_t)(row0 + wid*16 + srow) * 1024 + scol;
    const bf16_t* gA1 = gA0 + (size_t)64 * 1024;
    const bf16_t* gB0 = wb + (size_t)(col0 + wid*16 + srow) * 1024 + scol;
    const bf16_t* gB1 = gB0 + (size_t)64 * 1024;
    const int lOffA0 = (wid*16) * 32;
    const int lOffA1 = (64 + wid*16) * 32;

    // swizzled read slot: logical kg -> physical slot kg ^ ((row>>1)&3)
    const int aslot = (kg ^ ((ar >> 1) & 3)) * 8;

    f32x4 acc[4][4];
#pragma unroll
    for (int m = 0; m < 4; m++)
#pragma unroll
        for (int n = 0; n < 4; n++)
            acc[m][n] = (f32x4){0.f, 0.f, 0.f, 0.f};

    gload16(gA0, &sA[0][lOffA0]);
    gload16(gA1, &sA[0][lOffA1]);
    gload16(gB0, &sB[0][lOffA0]);
    gload16(gB1, &sB[0][lOffA1]);

    for (int ks = 0; ks < 32; ks++) {
        const int p = ks & 1;
        __syncthreads();
        if (ks + 1 < 32) {
            const int k = (ks + 1) * 32;
            gload16(gA0 + k, &sA[p^1][lOffA0]);
            gload16(gA1 + k, &sA[p^1][lOffA1]);
            gload16(gB0 + k, &sB[p^1][lOffA0]);
            gload16(gB1 + k, &sB[p^1][lOffA1]);
        }
        bf16x8 a[4], b[4];
#pragma unroll
        for (int rf = 0; rf < 4; rf++)
            a[rf] = *(const bf16x8*)&sA[p][(wr + rf*16 + ar)*32 + aslot];
#pragma unroll
        for (int cf = 0; cf < 4; cf++)
            b[cf] = *(const bf16x8*)&sB[p][(wc + cf*16 + ar)*32 + aslot];
#pragma unroll
        for (int rf = 0; rf < 4; rf++)
#pragma unroll
            for (int cf = 0; cf < 4; cf++)
                acc[rf][cf] = __builtin_amdgcn_mfma_f32_16x16x32_bf16(
                    a[rf], b[cf], acc[rf][cf], 0, 0, 0);
    }

    float s0 = 0.f, s1 = 0.f;
#pragma unroll
    for (int n = 0; n < 4; n++) {
        const int c = col0 + wc + n*16 + ar;
        const int which = c >> 10;
        const int cc = c & 1023;
        const float bias = (which == 0 ? bq : (which == 1 ? bk : bv))[cc];
        if (which < 2) {
            bf16_t* ob = (which == 0 ? qbh : kbh);
#pragma unroll
            for (int m = 0; m < 4; m++) {
#pragma unroll
                for (int j = 0; j < 4; j++) {
                    const int r = row0 + wr + m*16 + kg*4 + j;
                    const float val = acc[m][n][j] + bias;
                    ob[(size_t)r * 1024 + cc] = (bf16_t)val;
                    if (which == 0) s0 += val * val;
                    else s1 += val * val;
                }
            }
        } else {
            const int h2 = cc >> 6, d = cc & 63;
#pragma unroll
            for (int m = 0; m < 4; m++) {
#pragma unroll
                for (int j = 0; j < 4; j++) {
                    const int r = row0 + wr + m*16 + kg*4 + j;
                    const float val = acc[m][n][j] + bias;
                    const int b2 = r / 100;
                    const int s2 = r - b2 * 100;
                    vt[((size_t)(b2*16 + h2)*64 + d)*128 + s2] = (bf16_t)val;
                }
            }
        }
    }
    for (int off = 32; off; off >>= 1) {
        s0 += __shfl_xor(s0, off);
        s1 += __shfl_xor(s1, off);
    }
    if (lane == 0) {
        if (s0 != 0.f) atomicAdd(ssq + 0, s0);
        if (s1 != 0.f) atomicAdd(ssq + 1, s1);
    }
}

// ---------------- finalize norms ----------------
__global__ void knorm(float* sc) {
    if (threadIdx.x == 0) {
        sc[2] = rsqrtf(sc[0]);
        sc[3] = rsqrtf(sc[1]);
    }
}

// ---------------- phi via MFMA; phi_q pre-divided by den; layout [bh][s][m] ----------------
__global__ __launch_bounds__(256)
void kphi_mfma(const bf16_t* __restrict__ qbh, const bf16_t* __restrict__ kbh,
               const bf16_t* __restrict__ wrfb, const float* __restrict__ sc,
               bf16_t* __restrict__ phqb, bf16_t* __restrict__ phkb) {
    const int lane = threadIdx.x & 63;
    const int wid  = threadIdx.x >> 6;
    const int h    = blockIdx.y;
    const int bs0  = blockIdx.x * 256 + wid * 64;
    const int ar = lane & 15;
    const int kg = lane >> 4;

    bf16x8 bfr[4][2];
#pragma unroll
    for (int cf = 0; cf < 4; cf++)
#pragma unroll
        for (int ks = 0; ks < 2; ks++)
            bfr[cf][ks] = *(const bf16x8*)(wrfb +
                ((size_t)(h * 64 + cf * 16 + ar) * 64 + ks * 32 + kg * 8));

    f32x4 aq[4][4], ak[4][4];
#pragma unroll
    for (int rf = 0; rf < 4; rf++)
#pragma unroll
        for (int cf = 0; cf < 4; cf++) {
            aq[rf][cf] = (f32x4){0.f, 0.f, 0.f, 0.f};
            ak[rf][cf] = (f32x4){0.f, 0.f, 0.f, 0.f};
        }

#pragma unroll
    for (int rf = 0; rf < 4; rf++) {
        const size_t urow = ((size_t)(bs0 + rf*16 + ar) * 16 + h) * 64 + kg * 8;
        const bf16x8 a0 = *(const bf16x8*)(qbh + urow);
        const bf16x8 a1 = *(const bf16x8*)(qbh + urow + 32);
        const bf16x8 c0 = *(const bf16x8*)(kbh + urow);
        const bf16x8 c1 = *(const bf16x8*)(kbh + urow + 32);
#pragma unroll
        for (int cf = 0; cf < 4; cf++) {
            aq[rf][cf] = __builtin_amdgcn_mfma_f32_16x16x32_bf16(a0, bfr[cf][0], aq[rf][cf], 0, 0, 0);
            aq[rf][cf] = __builtin_amdgcn_mfma_f32_16x16x32_bf16(a1, bfr[cf][1], aq[rf][cf], 0, 0, 0);
            ak[rf][cf] = __builtin_amdgcn_mfma_f32_16x16x32_bf16(c0, bfr[cf][0], ak[rf][cf], 0, 0, 0);
            ak[rf][cf] = __builtin_amdgcn_mfma_f32_16x16x32_bf16(c1, bfr[cf][1], ak[rf][cf], 0, 0, 0);
        }
    }

    const float qs = sc[2];
    const float ksc = sc[3];
    const float CPHI = 0.009477041545882225f;  // exp(-0.5)/64

#pragma unroll
    for (int rf = 0; rf < 4; rf++) {
        float vq[4][4], vk[4][4];
        float t[4] = {0.f, 0.f, 0.f, 0.f};
#pragma unroll
        for (int cf = 0; cf < 4; cf++) {
#pragma unroll
            for (int j = 0; j < 4; j++) {
                const float q_ = expf(aq[rf][cf][j] * qs) * CPHI;
                const float k_ = expf(ak[rf][cf][j] * ksc) * CPHI;
                vq[cf][j] = q_;
                vk[cf][j] = k_;
                t[j] += q_ * k_;
            }
        }
#pragma unroll
        for (int j = 0; j < 4; j++) {
            t[j] += __shfl_xor(t[j], 1);
            t[j] += __shfl_xor(t[j], 2);
            t[j] += __shfl_xor(t[j], 4);
            t[j] += __shfl_xor(t[j], 8);
            t[j] = 1.0f / t[j];
        }
#pragma unroll
        for (int cf = 0; cf < 4; cf++) {
#pragma unroll
            for (int j = 0; j < 4; j++) {
                const int bs = bs0 + rf*16 + kg*4 + j;
                const int b = bs / 100;
                const int s = bs - b * 100;
                const size_t o = (((size_t)b*16 + h)*100 + s)*64 + cf*16 + ar;
                phqb[o] = (bf16_t)(vq[cf][j] * t[j]);   // phi_q / den
                phkb[o] = (bf16_t)vk[cf][j];
            }
        }
    }
}

// ---------------- P[s][s'] = sum_m phiq_s[s][m] * phik[s'][m]; [bh][100][128] bf16 ----------------
__global__ __launch_bounds__(256)
void kP(const bf16_t* __restrict__ phq, const bf16_t* __restrict__ phk,
        bf16_t* __restrict__ P) {
    const int lane = threadIdx.x & 63;
    const int w    = threadIdx.x >> 6;
    const int bh   = blockIdx.x;
    const int ar = lane & 15;
    const int kg = lane >> 4;
    const bf16_t* qb = phq + (size_t)bh * 6400;
    const bf16_t* kb = phk + (size_t)bh * 6400;

    bf16x8 bfr[7][2];
#pragma unroll
    for (int cf = 0; cf < 7; cf++) {
        int sp = cf*16 + ar; sp = sp > 99 ? 99 : sp;
#pragma unroll
        for (int ks = 0; ks < 2; ks++)
            bfr[cf][ks] = *(const bf16x8*)(kb + sp*64 + ks*32 + kg*8);
    }

#pragma unroll
    for (int rr = 0; rr < 2; rr++) {
        const int rf = w + rr*4;
        if (rf > 6) continue;
        int s = rf*16 + ar; s = s > 99 ? 99 : s;
        const bf16x8 a0 = *(const bf16x8*)(qb + s*64 + kg*8);
        const bf16x8 a1 = *(const bf16x8*)(qb + s*64 + 32 + kg*8);
        f32x4 acc[7];
#pragma unroll
        for (int cf = 0; cf < 7; cf++) acc[cf] = (f32x4){0.f,0.f,0.f,0.f};
#pragma unroll
        for (int cf = 0; cf < 7; cf++) {
            acc[cf] = __builtin_amdgcn_mfma_f32_16x16x32_bf16(a0, bfr[cf][0], acc[cf], 0, 0, 0);
            acc[cf] = __builtin_amdgcn_mfma_f32_16x16x32_bf16(a1, bfr[cf][1], acc[cf], 0, 0, 0);
        }
#pragma unroll
        for (int cf = 0; cf < 7; cf++) {
#pragma unroll
            for (int j = 0; j < 4; j++) {
                const int so = rf*16 + kg*4 + j;
                const int sp = cf*16 + ar;
                if (so < 100)
                    P[((size_t)bh*100 + so)*128 + sp] =
                        (bf16_t)(sp < 100 ? acc[cf][j] : 0.f);
            }
        }
#pragma unroll
        for (int j = 0; j < 4; j++) {       // zero pad cols [112,128)
            const int so = rf*16 + kg*4 + j;
            if (so < 100)
                P[((size_t)bh*100 + so)*128 + 112 + ar] = (bf16_t)0.f;
        }
    }
}

// ---------------- Wt[d][s'] = sum_t vt[d][t] * G[s'][t]; [bh][64][128] bf16 ----------------
__global__ __launch_bounds__(256)
void kw(const bf16_t* __restrict__ vt, const bf16_t* __restrict__ G,
        bf16_t* __restrict__ Wt) {
    const int lane = threadIdx.x & 63;
    const int w    = threadIdx.x >> 6;
    const int bh   = blockIdx.x;
    const int ar = lane & 15;
    const int kg = lane >> 4;
    const bf16_t* vb = vt + (size_t)bh * 8192;

    bf16x8 a[4];
#pragma unroll
    for (int ks = 0; ks < 4; ks++)
        a[ks] = *(const bf16x8*)(vb + (w*16 + ar)*128 + ks*32 + kg*8);

#pragma unroll
    for (int cf = 0; cf < 7; cf++) {
        f32x4 acc = (f32x4){0.f,0.f,0.f,0.f};
#pragma unroll
        for (int ks = 0; ks < 4; ks++) {
            const bf16x8 b = *(const bf16x8*)(G + (cf*16 + ar)*128 + ks*32 + kg*8);
            acc = __builtin_amdgcn_mfma_f32_16x16x32_bf16(a[ks], b, acc, 0, 0, 0);
        }
#pragma unroll
        for (int j = 0; j < 4; j++) {
            const int d = w*16 + kg*4 + j;
            const int sp = cf*16 + ar;
            Wt[((size_t)bh*64 + d)*128 + sp] = (bf16_t)acc[j];
        }
    }
#pragma unroll
    for (int j = 0; j < 4; j++) {           // zero pad cols [112,128)
        const int d = w*16 + kg*4 + j;
        Wt[((size_t)bh*64 + d)*128 + 112 + ar] = (bf16_t)0.f;
    }
}

// ---------------- out[s][d] = sum_s' P[s][s'] * Wt[d][s'] ----------------
__global__ __launch_bounds__(256)
void knum(const bf16_t* __restrict__ P, const bf16_t* __restrict__ Wt,
          float* __restrict__ out) {
    const int lane = threadIdx.x & 63;
    const int w    = threadIdx.x >> 6;
    const int bh   = blockIdx.x;
    const int b = bh >> 4, h = bh & 15;
    const int ar = lane & 15;
    const int kg = lane >> 4;
    const bf16_t* pb = P + (size_t)bh * 12800;
    const bf16_t* wb = Wt + (size_t)bh * 8192;

    bf16x8 bfr[4][4];
#pragma unroll
    for (int cf = 0; cf < 4; cf++)
#pragma unroll
        for (int ks = 0; ks < 4; ks++)
            bfr[cf][ks] = *(const bf16x8*)(wb + (cf*16 + ar)*128 + ks*32 + kg*8);

#pragma unroll
    for (int rr = 0; rr < 2; rr++) {
        const int rf = w + rr*4;
        if (rf > 6) continue;
        int s = rf*16 + ar; s = s > 99 ? 99 : s;
        bf16x8 a[4];
#pragma unroll
        for (int ks = 0; ks < 4; ks++)
            a[ks] = *(const bf16x8*)(pb + s*128 + ks*32 + kg*8);
        f32x4 acc[4];
#pragma unroll
        for (int cf = 0; cf < 4; cf++) acc[cf] = (f32x4){0.f,0.f,0.f,0.f};
#pragma unroll
        for (int cf = 0; cf < 4; cf++)
#pragma unroll
            for (int ks = 0; ks < 4; ks++)
                acc[cf] = __builtin_amdgcn_mfma_f32_16x16x32_bf16(a[ks], bfr[cf][ks], acc[cf], 0, 0, 0);
#pragma unroll
        for (int cf = 0; cf < 4; cf++) {
#pragma unroll
            for (int j = 0; j < 4; j++) {
                const int so = rf*16 + kg*4 + j;
                if (so < 100)
                    out[((size_t)(b*100 + so)*16 + h)*64 + cf*16 + ar] = acc[cf][j];
            }
        }
    }
}

extern "C" void kernel_launch(void* const* d_in, const int* in_sizes, int n_in,
                              void* d_out, int out_size, void* d_ws, size_t ws_size,
                              hipStream_t stream) {
    const float* x   = (const float*)d_in[0];
    const float* Wq  = (const float*)d_in[1];
    const float* bq  = (const float*)d_in[2];
    const float* Wk  = (const float*)d_in[3];
    const float* bk  = (const float*)d_in[4];
    const float* Wv  = (const float*)d_in[5];
    const float* bv  = (const float*)d_in[6];
    const float* Wrf = (const float*)d_in[7];
    const float* E   = (const float*)d_in[8];
    const float* F   = (const float*)d_in[9];
    float* out = (float*)d_out;

    char* ws = (char*)d_ws;
    bf16_t* qbh  = (bf16_t*)(ws + QBH_OFF);
    bf16_t* kbh  = (bf16_t*)(ws + KBH_OFF);
    bf16_t* vt   = (bf16_t*)(ws + VT_OFF);
    bf16_t* xb   = (bf16_t*)(ws + XB_OFF);
    bf16_t* phqb = (bf16_t*)(ws + PHQ_OFF);
    bf16_t* wb   = (bf16_t*)(ws + WB_OFF);
    bf16_t* wrfb = (bf16_t*)(ws + WRFB_OFF);
    bf16_t* G    = (bf16_t*)(ws + G_OFF);
    bf16_t* phkb = (bf16_t*)(ws + PHK_OFF);
    bf16_t* P    = (bf16_t*)(ws + P_OFF);
    bf16_t* Wt   = (bf16_t*)(ws + WT_OFF);
    float*  sc   = (float*)(ws + SC_OFF);

    hipMemsetAsync(sc, 0, 16, stream);
    hipMemsetAsync(vt, 0, 33554432ull, stream);   // zero t-pad [100,128)

    kconv_x<<<2048, 256, 0, stream>>>(x, xb, BS * 1024 / 4);
    kconv_w<<<1024, 256, 0, stream>>>(Wq, Wk, Wv, wb, 3 * 1024 * 1024 / 4);
    kconv_wrf<<<64, 256, 0, stream>>>(Wrf, wrfb, HH * 64 * 64 / 4);
    kG<<<56, 256, 0, stream>>>(E, F, G);

    dim3 ggrid(24, 100);   // 3072/128 cols x 12800/128 rows
    kgemm<<<ggrid, 256, 0, stream>>>(xb, wb, bq, bk, bv, qbh, kbh, vt, sc);

    knorm<<<1, 64, 0, stream>>>(sc);
    dim3 pgrid(50, 16);    // 12800/256 bs-tiles x 16 heads
    kphi_mfma<<<pgrid, 256, 0, stream>>>(qbh, kbh, wrfb, sc, phqb, phkb);

    kP<<<BQ * HH, 256, 0, stream>>>(phqb, phkb, P);
    kw<<<BQ * HH, 256, 0, stream>>>(vt, G, Wt);
    knum<<<BQ * HH, 256, 0, stream>>>(P, Wt, out);
}

// Round 6
// 300.980 us; speedup vs baseline: 4.4289x; 1.0622x over previous
//
#include <hip/hip_runtime.h>
#include <math.h>

// Problem constants
#define BQ 128
#define SQ 100
#define HH 16
#define LL 48
#define BS (BQ*SQ)        // 12800 rows

typedef __bf16 bf16_t;
typedef bf16_t bf16x8 __attribute__((ext_vector_type(8)));
typedef float f32x4 __attribute__((ext_vector_type(4)));

// Workspace byte offsets (peak ~197.3 MB)
#define QBH_OFF  0ull            // 26,214,400 q bf16 [bs][1024]      (dead after kphi)
#define KBH_OFF  26214400ull     // 26,214,400 k bf16                  (dead after kphi)
#define VT_OFF   52428800ull     // 33,554,432 v^T bf16 [bh][64][128]  (dead after kw)
#define XB_OFF   85983232ull     // 26,214,400 x bf16                  (dead after kgemm)
#define PHQ_OFF  85983232ull     // phi_q/den bf16 [bh][100][64] (over dead XB)
#define WB_OFF   112197632ull    // 6,291,456 Wcat bf16                (dead after kgemm)
#define WRFB_OFF 118489088ull    // 131,072 Wrf bf16                   (dead after kphi)
#define G_OFF    118620160ull    // 28,672 G bf16 [112][128]           (dead after kw)
#define PHK_OFF  118648832ull    // 26,214,400 phi_k bf16 [bh][100][64]
#define WT_OFF   0ull            // 33,554,432 W^T bf16 [bh][64][128] (over dead QBH/KBH)
#define SC_OFF   197292032ull    // 16 B scalars

__device__ __forceinline__ void gload16(const bf16_t* g, bf16_t* l) {
    __builtin_amdgcn_global_load_lds(
        (const __attribute__((address_space(1))) void*)g,
        (__attribute__((address_space(3))) void*)l, 16, 0, 0);
}

// ---------------- convert x -> bf16 ----------------
__global__ __launch_bounds__(256)
void kconv_x(const float* __restrict__ x, bf16_t* __restrict__ xb, int n4) {
    int i = blockIdx.x * blockDim.x + threadIdx.x;
    int stride = gridDim.x * blockDim.x;
    const f32x4* x4 = (const f32x4*)x;
    for (; i < n4; i += stride) {
        f32x4 v = x4[i];
        bf16_t* o = xb + 4*(size_t)i;
        o[0] = (bf16_t)v[0]; o[1] = (bf16_t)v[1];
        o[2] = (bf16_t)v[2]; o[3] = (bf16_t)v[3];
    }
}

// ---------------- convert Wq|Wk|Wv -> bf16 concatenated [3072][1024] ----------------
__global__ __launch_bounds__(256)
void kconv_w(const float* __restrict__ Wq, const float* __restrict__ Wk,
             const float* __restrict__ Wv, bf16_t* __restrict__ wb, int n4) {
    int i = blockIdx.x * blockDim.x + threadIdx.x;
    int stride = gridDim.x * blockDim.x;
    for (; i < n4; i += stride) {
        int f = i * 4;
        int row = f >> 10;
        int col = f & 1023;
        const float* src = (row < 1024) ? Wq : ((row < 2048) ? Wk : Wv);
        const f32x4 v = *(const f32x4*)(src + ((size_t)(row & 1023) << 10) + col);
        bf16_t* o = wb + (size_t)f;
        o[0] = (bf16_t)v[0]; o[1] = (bf16_t)v[1];
        o[2] = (bf16_t)v[2]; o[3] = (bf16_t)v[3];
    }
}

// ---------------- convert Wrf -> bf16 [16][64][64] ----------------
__global__ __launch_bounds__(256)
void kconv_wrf(const float* __restrict__ w, bf16_t* __restrict__ o, int n4) {
    int i = blockIdx.x * blockDim.x + threadIdx.x;
    if (i >= n4) return;
    f32x4 v = ((const f32x4*)w)[i];
    bf16_t* p = o + 4*(size_t)i;
    p[0] = (bf16_t)v[0]; p[1] = (bf16_t)v[1];
    p[2] = (bf16_t)v[2]; p[3] = (bf16_t)v[3];
}

// ---------------- G[s][t] = sum_l E[s][l]*F[t][l], zero-padded to [112][128] ----------------
__global__ __launch_bounds__(256)
void kG(const float* __restrict__ E, const float* __restrict__ F,
        bf16_t* __restrict__ G) {
    const int idx = blockIdx.x * 256 + threadIdx.x;   // 56*256 = 14336 = 112*128
    const int s = idx >> 7, t = idx & 127;
    float acc = 0.f;
    if (s < 100 && t < 100) {
#pragma unroll
        for (int l = 0; l < LL; l++) acc += E[s*LL+l] * F[t*LL+l];
    }
    G[idx] = (bf16_t)acc;
}

// ---------------- zero vt pad cols [100,128): bytes [200,256) of each 256B row ----------------
__global__ __launch_bounds__(256)
void kvpad(bf16_t* __restrict__ vt) {
    const int i = blockIdx.x * 256 + threadIdx.x;   // 131072 rows * 14 dwords
    if (i >= 131072 * 14) return;
    const int row = i / 14, dw = i - row * 14;
    ((unsigned int*)((char*)vt + (size_t)row * 256 + 200))[dw] = 0u;
}

// ---------------- fused QKV GEMM: 3-deep LDS pipeline, counted vmcnt ----------------
// q,k -> bf16 [bs][1024]; v -> bf16 transposed [bh][d][s] (vt, pad pre-zeroed)
__global__ __launch_bounds__(256)
void kgemm(const bf16_t* __restrict__ xb, const bf16_t* __restrict__ wb,
           const float* __restrict__ bq, const float* __restrict__ bk,
           const float* __restrict__ bv,
           bf16_t* __restrict__ qbh, bf16_t* __restrict__ kbh,
           bf16_t* __restrict__ vt, float* __restrict__ ssq) {
    __shared__ bf16_t sA[3][128*32];
    __shared__ bf16_t sB[3][128*32];   // 48 KiB total
    const int lane = threadIdx.x & 63;
    const int wid  = threadIdx.x >> 6;
    const int row0 = blockIdx.y * 128;
    const int col0 = blockIdx.x * 128;
    const int wr = (wid >> 1) * 64;
    const int wc = (wid & 1) * 64;
    const int ar = lane & 15;
    const int kg = lane >> 4;

    // staging: linear LDS dest, pre-swizzled global source slot
    const int srow = lane >> 2;
    const int sslot = (lane & 3) ^ ((lane >> 3) & 3);
    const int scol = sslot * 8;
    const bf16_t* gA0 = xb + (size_t)(row0 + wid*16 + srow) * 1024 + scol;
    const bf16_t* gA1 = gA0 + (size_t)64 * 1024;
    const bf16_t* gB0 = wb + (size_t)(col0 + wid*16 + srow) * 1024 + scol;
    const bf16_t* gB1 = gB0 + (size_t)64 * 1024;
    const int lOffA0 = (wid*16) * 32;
    const int lOffA1 = (64 + wid*16) * 32;

    // swizzled read slot: logical kg -> physical slot kg ^ ((row>>1)&3)
    const int aslot = (kg ^ ((ar >> 1) & 3)) * 8;

    f32x4 acc[4][4];
#pragma unroll
    for (int m = 0; m < 4; m++)
#pragma unroll
        for (int n = 0; n < 4; n++)
            acc[m][n] = (f32x4){0.f, 0.f, 0.f, 0.f};

#define STAGE(buf, t) do { const int kk_ = (t)*32; \
        gload16(gA0 + kk_, &sA[(buf)][lOffA0]); \
        gload16(gA1 + kk_, &sA[(buf)][lOffA1]); \
        gload16(gB0 + kk_, &sB[(buf)][lOffA0]); \
        gload16(gB1 + kk_, &sB[(buf)][lOffA1]); } while(0)

    STAGE(0, 0);
    STAGE(1, 1);

    for (int ks = 0; ks < 32; ks++) {
        // wait for tile ks's 4 loads (tile ks+1's may stay in flight), then sync
        if (ks < 31) asm volatile("s_waitcnt vmcnt(4)" ::: "memory");
        else         asm volatile("s_waitcnt vmcnt(0)" ::: "memory");
        __builtin_amdgcn_sched_barrier(0);
        __builtin_amdgcn_s_barrier();
        __builtin_amdgcn_sched_barrier(0);
        const int p = ks % 3;
        if (ks + 2 < 32) {
            const int nb = (ks + 2) % 3;   // read last at iter ks-1; safe past barrier
            STAGE(nb, ks + 2);
        }
        bf16x8 a[4], bb[4];
#pragma unroll
        for (int rf = 0; rf < 4; rf++)
            a[rf] = *(const bf16x8*)&sA[p][(wr + rf*16 + ar)*32 + aslot];
#pragma unroll
        for (int cf = 0; cf < 4; cf++)
            bb[cf] = *(const bf16x8*)&sB[p][(wc + cf*16 + ar)*32 + aslot];
#pragma unroll
        for (int rf = 0; rf < 4; rf++)
#pragma unroll
            for (int cf = 0; cf < 4; cf++)
                acc[rf][cf] = __builtin_amdgcn_mfma_f32_16x16x32_bf16(
                    a[rf], bb[cf], acc[rf][cf], 0, 0, 0);
    }
#undef STAGE

    float s0 = 0.f, s1 = 0.f;
#pragma unroll
    for (int n = 0; n < 4; n++) {
        const int c = col0 + wc + n*16 + ar;
        const int which = c >> 10;
        const int cc = c & 1023;
        const float bias = (which == 0 ? bq : (which == 1 ? bk : bv))[cc];
        if (which < 2) {
            bf16_t* ob = (which == 0 ? qbh : kbh);
#pragma unroll
            for (int m = 0; m < 4; m++) {
#pragma unroll
                for (int j = 0; j < 4; j++) {
                    const int r = row0 + wr + m*16 + kg*4 + j;
                    const float val = acc[m][n][j] + bias;
                    ob[(size_t)r * 1024 + cc] = (bf16_t)val;
                    if (which == 0) s0 += val * val;
                    else s1 += val * val;
                }
            }
        } else {
            const int h2 = cc >> 6, d = cc & 63;
#pragma unroll
            for (int m = 0; m < 4; m++) {
#pragma unroll
                for (int j = 0; j < 4; j++) {
                    const int r = row0 + wr + m*16 + kg*4 + j;
                    const float val = acc[m][n][j] + bias;
                    const int b2 = r / 100;
                    const int s2 = r - b2 * 100;
                    vt[((size_t)(b2*16 + h2)*64 + d)*128 + s2] = (bf16_t)val;
                }
            }
        }
    }
    for (int off = 32; off; off >>= 1) {
        s0 += __shfl_xor(s0, off);
        s1 += __shfl_xor(s1, off);
    }
    if (lane == 0) {
        if (s0 != 0.f) atomicAdd(ssq + 0, s0);
        if (s1 != 0.f) atomicAdd(ssq + 1, s1);
    }
}

// ---------------- finalize norms ----------------
__global__ void knorm(float* sc) {
    if (threadIdx.x == 0) {
        sc[2] = rsqrtf(sc[0]);
        sc[3] = rsqrtf(sc[1]);
    }
}

// ---------------- phi via MFMA; phi_q pre-divided by den; layout [bh][s][m] ----------------
__global__ __launch_bounds__(256)
void kphi_mfma(const bf16_t* __restrict__ qbh, const bf16_t* __restrict__ kbh,
               const bf16_t* __restrict__ wrfb, const float* __restrict__ sc,
               bf16_t* __restrict__ phqb, bf16_t* __restrict__ phkb) {
    const int lane = threadIdx.x & 63;
    const int wid  = threadIdx.x >> 6;
    const int h    = blockIdx.y;
    const int bs0  = blockIdx.x * 256 + wid * 64;
    const int ar = lane & 15;
    const int kg = lane >> 4;

    bf16x8 bfr[4][2];
#pragma unroll
    for (int cf = 0; cf < 4; cf++)
#pragma unroll
        for (int ks = 0; ks < 2; ks++)
            bfr[cf][ks] = *(const bf16x8*)(wrfb +
                ((size_t)(h * 64 + cf * 16 + ar) * 64 + ks * 32 + kg * 8));

    f32x4 aq[4][4], ak[4][4];
#pragma unroll
    for (int rf = 0; rf < 4; rf++)
#pragma unroll
        for (int cf = 0; cf < 4; cf++) {
            aq[rf][cf] = (f32x4){0.f, 0.f, 0.f, 0.f};
            ak[rf][cf] = (f32x4){0.f, 0.f, 0.f, 0.f};
        }

#pragma unroll
    for (int rf = 0; rf < 4; rf++) {
        const size_t urow = ((size_t)(bs0 + rf*16 + ar) * 16 + h) * 64 + kg * 8;
        const bf16x8 a0 = *(const bf16x8*)(qbh + urow);
        const bf16x8 a1 = *(const bf16x8*)(qbh + urow + 32);
        const bf16x8 c0 = *(const bf16x8*)(kbh + urow);
        const bf16x8 c1 = *(const bf16x8*)(kbh + urow + 32);
#pragma unroll
        for (int cf = 0; cf < 4; cf++) {
            aq[rf][cf] = __builtin_amdgcn_mfma_f32_16x16x32_bf16(a0, bfr[cf][0], aq[rf][cf], 0, 0, 0);
            aq[rf][cf] = __builtin_amdgcn_mfma_f32_16x16x32_bf16(a1, bfr[cf][1], aq[rf][cf], 0, 0, 0);
            ak[rf][cf] = __builtin_amdgcn_mfma_f32_16x16x32_bf16(c0, bfr[cf][0], ak[rf][cf], 0, 0, 0);
            ak[rf][cf] = __builtin_amdgcn_mfma_f32_16x16x32_bf16(c1, bfr[cf][1], ak[rf][cf], 0, 0, 0);
        }
    }

    const float qs = sc[2];
    const float ksc = sc[3];
    const float CPHI = 0.009477041545882225f;  // exp(-0.5)/64

#pragma unroll
    for (int rf = 0; rf < 4; rf++) {
        float vq[4][4], vk[4][4];
        float t[4] = {0.f, 0.f, 0.f, 0.f};
#pragma unroll
        for (int cf = 0; cf < 4; cf++) {
#pragma unroll
            for (int j = 0; j < 4; j++) {
                const float q_ = expf(aq[rf][cf][j] * qs) * CPHI;
                const float k_ = expf(ak[rf][cf][j] * ksc) * CPHI;
                vq[cf][j] = q_;
                vk[cf][j] = k_;
                t[j] += q_ * k_;
            }
        }
#pragma unroll
        for (int j = 0; j < 4; j++) {
            t[j] += __shfl_xor(t[j], 1);
            t[j] += __shfl_xor(t[j], 2);
            t[j] += __shfl_xor(t[j], 4);
            t[j] += __shfl_xor(t[j], 8);
            t[j] = 1.0f / t[j];
        }
#pragma unroll
        for (int cf = 0; cf < 4; cf++) {
#pragma unroll
            for (int j = 0; j < 4; j++) {
                const int bs = bs0 + rf*16 + kg*4 + j;
                const int b = bs / 100;
                const int s = bs - b * 100;
                const size_t o = (((size_t)b*16 + h)*100 + s)*64 + cf*16 + ar;
                phqb[o] = (bf16_t)(vq[cf][j] * t[j]);   // phi_q / den
                phkb[o] = (bf16_t)vk[cf][j];
            }
        }
    }
}

// ---------------- Wt[d][s'] = sum_t vt[d][t] * G[s'][t]; [bh][64][128] bf16 ----------------
__global__ __launch_bounds__(256)
void kw(const bf16_t* __restrict__ vt, const bf16_t* __restrict__ G,
        bf16_t* __restrict__ Wt) {
    const int lane = threadIdx.x & 63;
    const int w    = threadIdx.x >> 6;
    const int bh   = blockIdx.x;
    const int ar = lane & 15;
    const int kg = lane >> 4;
    const bf16_t* vb = vt + (size_t)bh * 8192;

    bf16x8 a[4];
#pragma unroll
    for (int ks = 0; ks < 4; ks++)
        a[ks] = *(const bf16x8*)(vb + (w*16 + ar)*128 + ks*32 + kg*8);

#pragma unroll
    for (int cf = 0; cf < 7; cf++) {
        f32x4 acc = (f32x4){0.f,0.f,0.f,0.f};
#pragma unroll
        for (int ks = 0; ks < 4; ks++) {
            const bf16x8 b = *(const bf16x8*)(G + (cf*16 + ar)*128 + ks*32 + kg*8);
            acc = __builtin_amdgcn_mfma_f32_16x16x32_bf16(a[ks], b, acc, 0, 0, 0);
        }
#pragma unroll
        for (int j = 0; j < 4; j++) {
            const int d = w*16 + kg*4 + j;
            const int sp = cf*16 + ar;
            Wt[((size_t)bh*64 + d)*128 + sp] = (bf16_t)acc[j];
        }
    }
#pragma unroll
    for (int j = 0; j < 4; j++) {           // zero pad cols [112,128)
        const int d = w*16 + kg*4 + j;
        Wt[((size_t)bh*64 + d)*128 + 112 + ar] = (bf16_t)0.f;
    }
}

// ---------------- fused P + numerator: P kept in LDS (XOR-swizzled) ----------------
// P[s][s'] = sum_m phiq_s[s][m]*phik[s'][m]; out[s][d] = sum_s' P[s][s']*Wt[d][s']
__global__ __launch_bounds__(256)
void kPnum(const bf16_t* __restrict__ phq, const bf16_t* __restrict__ phk,
           const bf16_t* __restrict__ Wt, float* __restrict__ out) {
    __shared__ bf16_t sP[112 * 128];   // rows >=100 unused; elem swizzle: col ^ ((row&7)<<3)
    const int lane = threadIdx.x & 63;
    const int w    = threadIdx.x >> 6;
    const int bh   = blockIdx.x;
    const int b = bh >> 4, h = bh & 15;
    const int ar = lane & 15;
    const int kg = lane >> 4;
    const bf16_t* qb = phq + (size_t)bh * 6400;
    const bf16_t* kb = phk + (size_t)bh * 6400;

    // ---- part 1: P -> LDS ----
    bf16x8 bfr[7][2];
#pragma unroll
    for (int cf = 0; cf < 7; cf++) {
        int sp = cf*16 + ar; sp = sp > 99 ? 99 : sp;
#pragma unroll
        for (int ks = 0; ks < 2; ks++)
            bfr[cf][ks] = *(const bf16x8*)(kb + sp*64 + ks*32 + kg*8);
    }

#pragma unroll
    for (int rr = 0; rr < 2; rr++) {
        const int rf = w + rr*4;
        if (rf > 6) continue;
        int s = rf*16 + ar; s = s > 99 ? 99 : s;
        const bf16x8 a0 = *(const bf16x8*)(qb + s*64 + kg*8);
        const bf16x8 a1 = *(const bf16x8*)(qb + s*64 + 32 + kg*8);
        f32x4 acc[7];
#pragma unroll
        for (int cf = 0; cf < 7; cf++) acc[cf] = (f32x4){0.f,0.f,0.f,0.f};
#pragma unroll
        for (int cf = 0; cf < 7; cf++) {
            acc[cf] = __builtin_amdgcn_mfma_f32_16x16x32_bf16(a0, bfr[cf][0], acc[cf], 0, 0, 0);
            acc[cf] = __builtin_amdgcn_mfma_f32_16x16x32_bf16(a1, bfr[cf][1], acc[cf], 0, 0, 0);
        }
#pragma unroll
        for (int cf = 0; cf < 7; cf++) {
#pragma unroll
            for (int j = 0; j < 4; j++) {
                const int so = rf*16 + kg*4 + j;
                const int sp = cf*16 + ar;
                if (so < 100)
                    sP[so*128 + (sp ^ ((so&7)<<3))] =
                        (bf16_t)(sp < 100 ? acc[cf][j] : 0.f);
            }
        }
#pragma unroll
        for (int j = 0; j < 4; j++) {       // zero cols [112,128)
            const int so = rf*16 + kg*4 + j;
            if (so < 100) {
                const int sp = 112 + ar;
                sP[so*128 + (sp ^ ((so&7)<<3))] = (bf16_t)0.f;
            }
        }
    }
    __syncthreads();

    // ---- part 2: out = P * Wt^T ----
    const bf16_t* wb = Wt + (size_t)bh * 8192;
    bf16x8 wfr[4][4];
#pragma unroll
    for (int cf = 0; cf < 4; cf++)
#pragma unroll
        for (int ks = 0; ks < 4; ks++)
            wfr[cf][ks] = *(const bf16x8*)(wb + (cf*16 + ar)*128 + ks*32 + kg*8);

#pragma unroll
    for (int rr = 0; rr < 2; rr++) {
        const int rf = w + rr*4;
        if (rf > 6) continue;
        int s = rf*16 + ar; s = s > 99 ? 99 : s;
        bf16x8 a[4];
#pragma unroll
        for (int ks = 0; ks < 4; ks++)
            a[ks] = *(const bf16x8*)&sP[s*128 + ((ks*32 + kg*8) ^ ((s&7)<<3))];
        f32x4 acc[4];
#pragma unroll
        for (int cf = 0; cf < 4; cf++) acc[cf] = (f32x4){0.f,0.f,0.f,0.f};
#pragma unroll
        for (int cf = 0; cf < 4; cf++)
#pragma unroll
            for (int ks = 0; ks < 4; ks++)
                acc[cf] = __builtin_amdgcn_mfma_f32_16x16x32_bf16(a[ks], wfr[cf][ks], acc[cf], 0, 0, 0);
#pragma unroll
        for (int cf = 0; cf < 4; cf++) {
#pragma unroll
            for (int j = 0; j < 4; j++) {
                const int so = rf*16 + kg*4 + j;
                if (so < 100)
                    out[((size_t)(b*100 + so)*16 + h)*64 + cf*16 + ar] = acc[cf][j];
            }
        }
    }
}

extern "C" void kernel_launch(void* const* d_in, const int* in_sizes, int n_in,
                              void* d_out, int out_size, void* d_ws, size_t ws_size,
                              hipStream_t stream) {
    const float* x   = (const float*)d_in[0];
    const float* Wq  = (const float*)d_in[1];
    const float* bq  = (const float*)d_in[2];
    const float* Wk  = (const float*)d_in[3];
    const float* bk  = (const float*)d_in[4];
    const float* Wv  = (const float*)d_in[5];
    const float* bv  = (const float*)d_in[6];
    const float* Wrf = (const float*)d_in[7];
    const float* E   = (const float*)d_in[8];
    const float* F   = (const float*)d_in[9];
    float* out = (float*)d_out;

    char* ws = (char*)d_ws;
    bf16_t* qbh  = (bf16_t*)(ws + QBH_OFF);
    bf16_t* kbh  = (bf16_t*)(ws + KBH_OFF);
    bf16_t* vt   = (bf16_t*)(ws + VT_OFF);
    bf16_t* xb   = (bf16_t*)(ws + XB_OFF);
    bf16_t* phqb = (bf16_t*)(ws + PHQ_OFF);
    bf16_t* wb   = (bf16_t*)(ws + WB_OFF);
    bf16_t* wrfb = (bf16_t*)(ws + WRFB_OFF);
    bf16_t* G    = (bf16_t*)(ws + G_OFF);
    bf16_t* phkb = (bf16_t*)(ws + PHK_OFF);
    bf16_t* Wt   = (bf16_t*)(ws + WT_OFF);
    float*  sc   = (float*)(ws + SC_OFF);

    hipMemsetAsync(sc, 0, 16, stream);

    kconv_x<<<2048, 256, 0, stream>>>(x, xb, BS * 1024 / 4);
    kconv_w<<<1024, 256, 0, stream>>>(Wq, Wk, Wv, wb, 3 * 1024 * 1024 / 4);
    kconv_wrf<<<64, 256, 0, stream>>>(Wrf, wrfb, HH * 64 * 64 / 4);
    kG<<<56, 256, 0, stream>>>(E, F, G);
    kvpad<<<7168, 256, 0, stream>>>(vt);

    dim3 ggrid(24, 100);   // 3072/128 cols x 12800/128 rows
    kgemm<<<ggrid, 256, 0, stream>>>(xb, wb, bq, bk, bv, qbh, kbh, vt, sc);

    knorm<<<1, 64, 0, stream>>>(sc);
    dim3 pgrid(50, 16);    // 12800/256 bs-tiles x 16 heads
    kphi_mfma<<<pgrid, 256, 0, stream>>>(qbh, kbh, wrfb, sc, phqb, phkb);

    kw<<<BQ * HH, 256, 0, stream>>>(vt, G, Wt);
    kPnum<<<BQ * HH, 256, 0, stream>>>(phqb, phkb, Wt, out);
}

// Round 7
// 271.606 us; speedup vs baseline: 4.9079x; 1.1082x over previous
//
#include <hip/hip_runtime.h>
#include <math.h>

// Problem constants
#define BQ 128
#define SQ 100
#define HH 16
#define LL 48
#define BS (BQ*SQ)        // 12800 rows

typedef __bf16 bf16_t;
typedef bf16_t bf16x8 __attribute__((ext_vector_type(8)));
typedef float f32x4 __attribute__((ext_vector_type(4)));

// Workspace byte offsets (peak ~197.3 MB)
#define QBH_OFF  0ull            // 26,214,400 q bf16 [bs][1024]      (dead after kphi)
#define KBH_OFF  26214400ull     // 26,214,400 k bf16                  (dead after kphi)
#define VT_OFF   52428800ull     // 33,554,432 v^T bf16 [bh][64][128]  (dead after kw)
#define XB_OFF   85983232ull     // 26,214,400 x bf16                  (dead after kgemm)
#define PHQ_OFF  85983232ull     // phi_q/den bf16 [bh][100][64] (over dead XB)
#define WB_OFF   112197632ull    // 6,291,456 Wcat bf16                (dead after kgemm)
#define WRFB_OFF 118489088ull    // 131,072 Wrf bf16                   (dead after kphi)
#define G_OFF    118620160ull    // 28,672 G bf16 [112][128]           (dead after kw)
#define PHK_OFF  118648832ull    // 26,214,400 phi_k bf16 [bh][100][64]
#define WT_OFF   0ull            // 33,554,432 W^T bf16 [bh][64][128] (over dead QBH/KBH)
#define SC_OFF   197292032ull    // 16 B scalars

__device__ __forceinline__ void gload16(const bf16_t* g, bf16_t* l) {
    __builtin_amdgcn_global_load_lds(
        (const __attribute__((address_space(1))) void*)g,
        (__attribute__((address_space(3))) void*)l, 16, 0, 0);
}

// ---------------- convert x -> bf16 ----------------
__global__ __launch_bounds__(256)
void kconv_x(const float* __restrict__ x, bf16_t* __restrict__ xb, int n4) {
    int i = blockIdx.x * blockDim.x + threadIdx.x;
    int stride = gridDim.x * blockDim.x;
    const f32x4* x4 = (const f32x4*)x;
    for (; i < n4; i += stride) {
        f32x4 v = x4[i];
        bf16_t* o = xb + 4*(size_t)i;
        o[0] = (bf16_t)v[0]; o[1] = (bf16_t)v[1];
        o[2] = (bf16_t)v[2]; o[3] = (bf16_t)v[3];
    }
}

// ---------------- convert Wq|Wk|Wv -> bf16 concatenated [3072][1024] ----------------
__global__ __launch_bounds__(256)
void kconv_w(const float* __restrict__ Wq, const float* __restrict__ Wk,
             const float* __restrict__ Wv, bf16_t* __restrict__ wb, int n4) {
    int i = blockIdx.x * blockDim.x + threadIdx.x;
    int stride = gridDim.x * blockDim.x;
    for (; i < n4; i += stride) {
        int f = i * 4;
        int row = f >> 10;
        int col = f & 1023;
        const float* src = (row < 1024) ? Wq : ((row < 2048) ? Wk : Wv);
        const f32x4 v = *(const f32x4*)(src + ((size_t)(row & 1023) << 10) + col);
        bf16_t* o = wb + (size_t)f;
        o[0] = (bf16_t)v[0]; o[1] = (bf16_t)v[1];
        o[2] = (bf16_t)v[2]; o[3] = (bf16_t)v[3];
    }
}

// ---------------- convert Wrf -> bf16 [16][64][64] ----------------
__global__ __launch_bounds__(256)
void kconv_wrf(const float* __restrict__ w, bf16_t* __restrict__ o, int n4) {
    int i = blockIdx.x * blockDim.x + threadIdx.x;
    if (i >= n4) return;
    f32x4 v = ((const f32x4*)w)[i];
    bf16_t* p = o + 4*(size_t)i;
    p[0] = (bf16_t)v[0]; p[1] = (bf16_t)v[1];
    p[2] = (bf16_t)v[2]; p[3] = (bf16_t)v[3];
}

// ---------------- G[s][t] = sum_l E[s][l]*F[t][l], zero-padded to [112][128] ----------------
__global__ __launch_bounds__(256)
void kG(const float* __restrict__ E, const float* __restrict__ F,
        bf16_t* __restrict__ G) {
    const int idx = blockIdx.x * 256 + threadIdx.x;   // 56*256 = 14336 = 112*128
    const int s = idx >> 7, t = idx & 127;
    float acc = 0.f;
    if (s < 100 && t < 100) {
#pragma unroll
        for (int l = 0; l < LL; l++) acc += E[s*LL+l] * F[t*LL+l];
    }
    G[idx] = (bf16_t)acc;
}

// ---------------- zero vt pad cols [100,128): bytes [200,256) of each 256B row ----------------
__global__ __launch_bounds__(256)
void kvpad(bf16_t* __restrict__ vt) {
    const int i = blockIdx.x * 256 + threadIdx.x;   // 131072 rows * 14 dwords
    if (i >= 131072 * 14) return;
    const int row = i / 14, dw = i - row * 14;
    ((unsigned int*)((char*)vt + (size_t)row * 256 + 200))[dw] = 0u;
}

// ---------------- fused QKV GEMM: 3-deep LDS pipeline + vectorized LDS epilogue ----------
// blocks x in [0,8): q; [8,16): k; [16,24): v (block-uniform output type).
// q,k -> bf16 [bs][1024]; v -> bf16 transposed [bh][d][s] (vt, pad pre-zeroed)
__global__ __launch_bounds__(256)
void kgemm(const bf16_t* __restrict__ xb, const bf16_t* __restrict__ wb,
           const float* __restrict__ bq, const float* __restrict__ bk,
           const float* __restrict__ bv,
           bf16_t* __restrict__ qbh, bf16_t* __restrict__ kbh,
           bf16_t* __restrict__ vt, float* __restrict__ ssq) {
    __shared__ __align__(16) bf16_t smem[24576];   // 48 KiB: 3xA(4096) | 3xB(4096); epilogue reuses [0,16384)
    bf16_t* sA = smem;            // sA[buf] = smem + buf*4096
    bf16_t* sB = smem + 12288;    // sB[buf] = smem + 12288 + buf*4096
    const int lane = threadIdx.x & 63;
    const int wid  = threadIdx.x >> 6;
    const int row0 = blockIdx.y * 128;
    const int col0 = blockIdx.x * 128;
    const int wr = (wid >> 1) * 64;
    const int wc = (wid & 1) * 64;
    const int ar = lane & 15;
    const int kg = lane >> 4;

    // staging: linear LDS dest, pre-swizzled global source slot
    const int srow = lane >> 2;
    const int sslot = (lane & 3) ^ ((lane >> 3) & 3);
    const int scol = sslot * 8;
    const bf16_t* gA0 = xb + (size_t)(row0 + wid*16 + srow) * 1024 + scol;
    const bf16_t* gA1 = gA0 + (size_t)64 * 1024;
    const bf16_t* gB0 = wb + (size_t)(col0 + wid*16 + srow) * 1024 + scol;
    const bf16_t* gB1 = gB0 + (size_t)64 * 1024;
    const int lOffA0 = (wid*16) * 32;
    const int lOffA1 = (64 + wid*16) * 32;

    // swizzled read slot: logical kg -> physical slot kg ^ ((row>>1)&3)
    const int aslot = (kg ^ ((ar >> 1) & 3)) * 8;

    f32x4 acc[4][4];
#pragma unroll
    for (int m = 0; m < 4; m++)
#pragma unroll
        for (int n = 0; n < 4; n++)
            acc[m][n] = (f32x4){0.f, 0.f, 0.f, 0.f};

#define STAGE(buf, t) do { const int kk_ = (t)*32; \
        gload16(gA0 + kk_, sA + (buf)*4096 + lOffA0); \
        gload16(gA1 + kk_, sA + (buf)*4096 + lOffA1); \
        gload16(gB0 + kk_, sB + (buf)*4096 + lOffA0); \
        gload16(gB1 + kk_, sB + (buf)*4096 + lOffA1); } while(0)

    STAGE(0, 0);
    STAGE(1, 1);

    for (int ks = 0; ks < 32; ks++) {
        // wait for tile ks's 4 loads (tile ks+1's may stay in flight), then sync
        if (ks < 31) asm volatile("s_waitcnt vmcnt(4)" ::: "memory");
        else         asm volatile("s_waitcnt vmcnt(0)" ::: "memory");
        __builtin_amdgcn_sched_barrier(0);
        __builtin_amdgcn_s_barrier();
        __builtin_amdgcn_sched_barrier(0);
        const int p = ks % 3;
        if (ks + 2 < 32) {
            const int nb = (ks + 2) % 3;   // read last at iter ks-1; safe past barrier
            STAGE(nb, ks + 2);
        }
        bf16x8 a[4], bb[4];
#pragma unroll
        for (int rf = 0; rf < 4; rf++)
            a[rf] = *(const bf16x8*)&sA[p*4096 + (wr + rf*16 + ar)*32 + aslot];
#pragma unroll
        for (int cf = 0; cf < 4; cf++)
            bb[cf] = *(const bf16x8*)&sB[p*4096 + (wc + cf*16 + ar)*32 + aslot];
#pragma unroll
        for (int rf = 0; rf < 4; rf++)
#pragma unroll
            for (int cf = 0; cf < 4; cf++)
                acc[rf][cf] = __builtin_amdgcn_mfma_f32_16x16x32_bf16(
                    a[rf], bb[cf], acc[rf][cf], 0, 0, 0);
    }
#undef STAGE

    const int which = col0 >> 10;        // block-uniform: 0=q 1=k 2=v
    const int cc0 = col0 & 1023;

    __syncthreads();   // done reading sA/sB; epilogue reuses smem[0,16384)

    float ss = 0.f;
    if (which < 2) {
        // row-major swizzled tile: smem[r*128 + (c ^ ((r&7)<<3))]
#pragma unroll
        for (int n = 0; n < 4; n++) {
            const float bias = (which == 0 ? bq : bk)[cc0 + wc + n*16 + ar];
            const int c = wc + n*16 + ar;
#pragma unroll
            for (int m = 0; m < 4; m++) {
#pragma unroll
                for (int j = 0; j < 4; j++) {
                    const int r = wr + m*16 + kg*4 + j;
                    const float val = acc[m][n][j] + bias;
                    ss += val * val;
                    smem[r*128 + (c ^ ((r&7)<<3))] = (bf16_t)val;
                }
            }
        }
    } else {
        // transposed swizzled tile: smem[c*128 + (r ^ ((c&7)<<3))]
#pragma unroll
        for (int n = 0; n < 4; n++) {
            const float bias = bv[cc0 + wc + n*16 + ar];
            const int c = wc + n*16 + ar;
#pragma unroll
            for (int m = 0; m < 4; m++) {
#pragma unroll
                for (int j = 0; j < 4; j++) {
                    const int r = wr + m*16 + kg*4 + j;
                    const float val = acc[m][n][j] + bias;
                    smem[c*128 + (r ^ ((c&7)<<3))] = (bf16_t)val;
                }
            }
        }
    }
    __syncthreads();

    if (which < 2) {
        bf16_t* ob = (which == 0) ? qbh : kbh;
#pragma unroll
        for (int i = 0; i < 8; i++) {
            const int e = i*2048 + threadIdx.x*8;
            const int r = e >> 7;
            const int c0 = e & 127;
            const bf16x8 chunk = *(const bf16x8*)&smem[r*128 + (c0 ^ ((r&7)<<3))];
            *(bf16x8*)(ob + (size_t)(row0 + r)*1024 + cc0 + c0) = chunk;
        }
        // sum-of-squares reduction
        for (int off = 32; off; off >>= 1) ss += __shfl_xor(ss, off);
        if (lane == 0 && ss != 0.f) atomicAdd(ssq + which, ss);
    } else {
#pragma unroll
        for (int i = 0; i < 8; i++) {
            const int e = i*2048 + threadIdx.x*8;
            const int c = e >> 7;
            const int r0 = e & 127;
            const bf16x8 chunk = *(const bf16x8*)&smem[c*128 + (r0 ^ ((c&7)<<3))];
            const int cc = cc0 + c;
            const int h2 = cc >> 6, d = cc & 63;
            const int rg = row0 + r0;
            const int b2 = rg / 100;
            const int s2 = rg - b2*100;
            if (s2 <= 92) {
                *(bf16x8*)(vt + ((size_t)(b2*16 + h2)*64 + d)*128 + s2) = chunk;
            } else {
#pragma unroll
                for (int t = 0; t < 8; t++) {
                    const int rgt = rg + t;
                    const int b3 = rgt / 100;
                    const int s3 = rgt - b3*100;
                    vt[((size_t)(b3*16 + h2)*64 + d)*128 + s3] = chunk[t];
                }
            }
        }
    }
}

// ---------------- finalize norms ----------------
__global__ void knorm(float* sc) {
    if (threadIdx.x == 0) {
        sc[2] = rsqrtf(sc[0]);
        sc[3] = rsqrtf(sc[1]);
    }
}

// ---------------- phi via MFMA; phi_q pre-divided by den; layout [bh][s][m] ----------------
__global__ __launch_bounds__(256)
void kphi_mfma(const bf16_t* __restrict__ qbh, const bf16_t* __restrict__ kbh,
               const bf16_t* __restrict__ wrfb, const float* __restrict__ sc,
               bf16_t* __restrict__ phqb, bf16_t* __restrict__ phkb) {
    const int lane = threadIdx.x & 63;
    const int wid  = threadIdx.x >> 6;
    const int h    = blockIdx.y;
    const int bs0  = blockIdx.x * 256 + wid * 64;
    const int ar = lane & 15;
    const int kg = lane >> 4;

    bf16x8 bfr[4][2];
#pragma unroll
    for (int cf = 0; cf < 4; cf++)
#pragma unroll
        for (int ks = 0; ks < 2; ks++)
            bfr[cf][ks] = *(const bf16x8*)(wrfb +
                ((size_t)(h * 64 + cf * 16 + ar) * 64 + ks * 32 + kg * 8));

    f32x4 aq[4][4], ak[4][4];
#pragma unroll
    for (int rf = 0; rf < 4; rf++)
#pragma unroll
        for (int cf = 0; cf < 4; cf++) {
            aq[rf][cf] = (f32x4){0.f, 0.f, 0.f, 0.f};
            ak[rf][cf] = (f32x4){0.f, 0.f, 0.f, 0.f};
        }

#pragma unroll
    for (int rf = 0; rf < 4; rf++) {
        const size_t urow = ((size_t)(bs0 + rf*16 + ar) * 16 + h) * 64 + kg * 8;
        const bf16x8 a0 = *(const bf16x8*)(qbh + urow);
        const bf16x8 a1 = *(const bf16x8*)(qbh + urow + 32);
        const bf16x8 c0 = *(const bf16x8*)(kbh + urow);
        const bf16x8 c1 = *(const bf16x8*)(kbh + urow + 32);
#pragma unroll
        for (int cf = 0; cf < 4; cf++) {
            aq[rf][cf] = __builtin_amdgcn_mfma_f32_16x16x32_bf16(a0, bfr[cf][0], aq[rf][cf], 0, 0, 0);
            aq[rf][cf] = __builtin_amdgcn_mfma_f32_16x16x32_bf16(a1, bfr[cf][1], aq[rf][cf], 0, 0, 0);
            ak[rf][cf] = __builtin_amdgcn_mfma_f32_16x16x32_bf16(c0, bfr[cf][0], ak[rf][cf], 0, 0, 0);
            ak[rf][cf] = __builtin_amdgcn_mfma_f32_16x16x32_bf16(c1, bfr[cf][1], ak[rf][cf], 0, 0, 0);
        }
    }

    const float qs = sc[2];
    const float ksc = sc[3];
    const float CPHI = 0.009477041545882225f;  // exp(-0.5)/64

#pragma unroll
    for (int rf = 0; rf < 4; rf++) {
        float vq[4][4], vk[4][4];
        float t[4] = {0.f, 0.f, 0.f, 0.f};
#pragma unroll
        for (int cf = 0; cf < 4; cf++) {
#pragma unroll
            for (int j = 0; j < 4; j++) {
                const float q_ = expf(aq[rf][cf][j] * qs) * CPHI;
                const float k_ = expf(ak[rf][cf][j] * ksc) * CPHI;
                vq[cf][j] = q_;
                vk[cf][j] = k_;
                t[j] += q_ * k_;
            }
        }
#pragma unroll
        for (int j = 0; j < 4; j++) {
            t[j] += __shfl_xor(t[j], 1);
            t[j] += __shfl_xor(t[j], 2);
            t[j] += __shfl_xor(t[j], 4);
            t[j] += __shfl_xor(t[j], 8);
            t[j] = 1.0f / t[j];
        }
#pragma unroll
        for (int cf = 0; cf < 4; cf++) {
#pragma unroll
            for (int j = 0; j < 4; j++) {
                const int bs = bs0 + rf*16 + kg*4 + j;
                const int b = bs / 100;
                const int s = bs - b * 100;
                const size_t o = (((size_t)b*16 + h)*100 + s)*64 + cf*16 + ar;
                phqb[o] = (bf16_t)(vq[cf][j] * t[j]);   // phi_q / den
                phkb[o] = (bf16_t)vk[cf][j];
            }
        }
    }
}

// ---------------- Wt[d][s'] = sum_t vt[d][t] * G[s'][t]; [bh][64][128] bf16 ----------------
__global__ __launch_bounds__(256)
void kw(const bf16_t* __restrict__ vt, const bf16_t* __restrict__ G,
        bf16_t* __restrict__ Wt) {
    const int lane = threadIdx.x & 63;
    const int w    = threadIdx.x >> 6;
    const int bh   = blockIdx.x;
    const int ar = lane & 15;
    const int kg = lane >> 4;
    const bf16_t* vb = vt + (size_t)bh * 8192;

    bf16x8 a[4];
#pragma unroll
    for (int ks = 0; ks < 4; ks++)
        a[ks] = *(const bf16x8*)(vb + (w*16 + ar)*128 + ks*32 + kg*8);

#pragma unroll
    for (int cf = 0; cf < 7; cf++) {
        f32x4 acc = (f32x4){0.f,0.f,0.f,0.f};
#pragma unroll
        for (int ks = 0; ks < 4; ks++) {
            const bf16x8 b = *(const bf16x8*)(G + (cf*16 + ar)*128 + ks*32 + kg*8);
            acc = __builtin_amdgcn_mfma_f32_16x16x32_bf16(a[ks], b, acc, 0, 0, 0);
        }
#pragma unroll
        for (int j = 0; j < 4; j++) {
            const int d = w*16 + kg*4 + j;
            const int sp = cf*16 + ar;
            Wt[((size_t)bh*64 + d)*128 + sp] = (bf16_t)acc[j];
        }
    }
#pragma unroll
    for (int j = 0; j < 4; j++) {           // zero pad cols [112,128)
        const int d = w*16 + kg*4 + j;
        Wt[((size_t)bh*64 + d)*128 + 112 + ar] = (bf16_t)0.f;
    }
}

// ---------------- fused P + numerator: P kept in LDS (XOR-swizzled) ----------------
// P[s][s'] = sum_m phiq_s[s][m]*phik[s'][m]; out[s][d] = sum_s' P[s][s']*Wt[d][s']
__global__ __launch_bounds__(256)
void kPnum(const bf16_t* __restrict__ phq, const bf16_t* __restrict__ phk,
           const bf16_t* __restrict__ Wt, float* __restrict__ out) {
    __shared__ bf16_t sP[112 * 128];   // rows >=100 unused; elem swizzle: col ^ ((row&7)<<3)
    const int lane = threadIdx.x & 63;
    const int w    = threadIdx.x >> 6;
    const int bh   = blockIdx.x;
    const int b = bh >> 4, h = bh & 15;
    const int ar = lane & 15;
    const int kg = lane >> 4;
    const bf16_t* qb = phq + (size_t)bh * 6400;
    const bf16_t* kb = phk + (size_t)bh * 6400;

    // ---- part 1: P -> LDS ----
    bf16x8 bfr[7][2];
#pragma unroll
    for (int cf = 0; cf < 7; cf++) {
        int sp = cf*16 + ar; sp = sp > 99 ? 99 : sp;
#pragma unroll
        for (int ks = 0; ks < 2; ks++)
            bfr[cf][ks] = *(const bf16x8*)(kb + sp*64 + ks*32 + kg*8);
    }

#pragma unroll
    for (int rr = 0; rr < 2; rr++) {
        const int rf = w + rr*4;
        if (rf > 6) continue;
        int s = rf*16 + ar; s = s > 99 ? 99 : s;
        const bf16x8 a0 = *(const bf16x8*)(qb + s*64 + kg*8);
        const bf16x8 a1 = *(const bf16x8*)(qb + s*64 + 32 + kg*8);
        f32x4 acc[7];
#pragma unroll
        for (int cf = 0; cf < 7; cf++) acc[cf] = (f32x4){0.f,0.f,0.f,0.f};
#pragma unroll
        for (int cf = 0; cf < 7; cf++) {
            acc[cf] = __builtin_amdgcn_mfma_f32_16x16x32_bf16(a0, bfr[cf][0], acc[cf], 0, 0, 0);
            acc[cf] = __builtin_amdgcn_mfma_f32_16x16x32_bf16(a1, bfr[cf][1], acc[cf], 0, 0, 0);
        }
#pragma unroll
        for (int cf = 0; cf < 7; cf++) {
#pragma unroll
            for (int j = 0; j < 4; j++) {
                const int so = rf*16 + kg*4 + j;
                const int sp = cf*16 + ar;
                if (so < 100)
                    sP[so*128 + (sp ^ ((so&7)<<3))] =
                        (bf16_t)(sp < 100 ? acc[cf][j] : 0.f);
            }
        }
#pragma unroll
        for (int j = 0; j < 4; j++) {       // zero cols [112,128)
            const int so = rf*16 + kg*4 + j;
            if (so < 100) {
                const int sp = 112 + ar;
                sP[so*128 + (sp ^ ((so&7)<<3))] = (bf16_t)0.f;
            }
        }
    }
    __syncthreads();

    // ---- part 2: out = P * Wt^T ----
    const bf16_t* wb = Wt + (size_t)bh * 8192;
    bf16x8 wfr[4][4];
#pragma unroll
    for (int cf = 0; cf < 4; cf++)
#pragma unroll
        for (int ks = 0; ks < 4; ks++)
            wfr[cf][ks] = *(const bf16x8*)(wb + (cf*16 + ar)*128 + ks*32 + kg*8);

#pragma unroll
    for (int rr = 0; rr < 2; rr++) {
        const int rf = w + rr*4;
        if (rf > 6) continue;
        int s = rf*16 + ar; s = s > 99 ? 99 : s;
        bf16x8 a[4];
#pragma unroll
        for (int ks = 0; ks < 4; ks++)
            a[ks] = *(const bf16x8*)&sP[s*128 + ((ks*32 + kg*8) ^ ((s&7)<<3))];
        f32x4 acc[4];
#pragma unroll
        for (int cf = 0; cf < 4; cf++) acc[cf] = (f32x4){0.f,0.f,0.f,0.f};
#pragma unroll
        for (int cf = 0; cf < 4; cf++)
#pragma unroll
            for (int ks = 0; ks < 4; ks++)
                acc[cf] = __builtin_amdgcn_mfma_f32_16x16x32_bf16(a[ks], wfr[cf][ks], acc[cf], 0, 0, 0);
#pragma unroll
        for (int cf = 0; cf < 4; cf++) {
#pragma unroll
            for (int j = 0; j < 4; j++) {
                const int so = rf*16 + kg*4 + j;
                if (so < 100)
                    out[((size_t)(b*100 + so)*16 + h)*64 + cf*16 + ar] = acc[cf][j];
            }
        }
    }
}

extern "C" void kernel_launch(void* const* d_in, const int* in_sizes, int n_in,
                              void* d_out, int out_size, void* d_ws, size_t ws_size,
                              hipStream_t stream) {
    const float* x   = (const float*)d_in[0];
    const float* Wq  = (const float*)d_in[1];
    const float* bq  = (const float*)d_in[2];
    const float* Wk  = (const float*)d_in[3];
    const float* bk  = (const float*)d_in[4];
    const float* Wv  = (const float*)d_in[5];
    const float* bv  = (const float*)d_in[6];
    const float* Wrf = (const float*)d_in[7];
    const float* E   = (const float*)d_in[8];
    const float* F   = (const float*)d_in[9];
    float* out = (float*)d_out;

    char* ws = (char*)d_ws;
    bf16_t* qbh  = (bf16_t*)(ws + QBH_OFF);
    bf16_t* kbh  = (bf16_t*)(ws + KBH_OFF);
    bf16_t* vt   = (bf16_t*)(ws + VT_OFF);
    bf16_t* xb   = (bf16_t*)(ws + XB_OFF);
    bf16_t* phqb = (bf16_t*)(ws + PHQ_OFF);
    bf16_t* wb   = (bf16_t*)(ws + WB_OFF);
    bf16_t* wrfb = (bf16_t*)(ws + WRFB_OFF);
    bf16_t* G    = (bf16_t*)(ws + G_OFF);
    bf16_t* phkb = (bf16_t*)(ws + PHK_OFF);
    bf16_t* Wt   = (bf16_t*)(ws + WT_OFF);
    float*  sc   = (float*)(ws + SC_OFF);

    hipMemsetAsync(sc, 0, 16, stream);

    kconv_x<<<2048, 256, 0, stream>>>(x, xb, BS * 1024 / 4);
    kconv_w<<<1024, 256, 0, stream>>>(Wq, Wk, Wv, wb, 3 * 1024 * 1024 / 4);
    kconv_wrf<<<64, 256, 0, stream>>>(Wrf, wrfb, HH * 64 * 64 / 4);
    kG<<<56, 256, 0, stream>>>(E, F, G);
    kvpad<<<7168, 256, 0, stream>>>(vt);

    dim3 ggrid(24, 100);   // 3072/128 cols x 12800/128 rows
    kgemm<<<ggrid, 256, 0, stream>>>(xb, wb, bq, bk, bv, qbh, kbh, vt, sc);

    knorm<<<1, 64, 0, stream>>>(sc);
    dim3 pgrid(50, 16);    // 12800/256 bs-tiles x 16 heads
    kphi_mfma<<<pgrid, 256, 0, stream>>>(qbh, kbh, wrfb, sc, phqb, phkb);

    kw<<<BQ * HH, 256, 0, stream>>>(vt, G, Wt);
    kPnum<<<BQ * HH, 256, 0, stream>>>(phqb, phkb, Wt, out);
}